// Round 2
// baseline (626.111 us; speedup 1.0000x reference)
//
#include <hip/hip_runtime.h>

// R-GCN basis-decomposed layer.
// out[n] = bias + f[n]@W[16] + sum_{r<16} (1/deg_r(n)) * (sum_{nb in N_r(n)} f[nb]) @ W[r]
// W[r] = sum_b comps[r,b] * bases[b]   =>  out[n] = bias + aggb[n,2048] @ basesFlat[2048,256]
// where aggb[n, b*256+i] = comps[16,b]*f[n,i] + sum_r comps[r,b]/deg_r(n) * relsum[r,n,i]
//
// ws (6.2 MB): deg/cursor[480000] | row_ptr[480001] | col[600000] | blksum[469]
// CSR keyed by idx = node*16 + rel  ->  each node's edges are ONE contiguous col range,
// col entries packed (rel<<16)|srcNode.

namespace {
constexpr int kN     = 30000;
constexpr int kR0    = 8;
constexpr int kNRel  = 16;                 // aggregated relation slots per node
constexpr int kIN    = 256;
constexpr int kOUT   = 256;
constexpr int kE     = 300000;
constexpr int kNB    = 8;
constexpr int kRows  = kN * kNRel;         // 480000
constexpr int kMsgs  = 2 * kE;             // 600000
constexpr int kScanBlk  = 1024;
constexpr int kNScanBlk = (kRows + kScanBlk - 1) / kScanBlk;   // 469
static_assert(kNScanBlk <= 512, "scan2 single block must cover block sums");
}

__global__ void k_count(const int* __restrict__ t, int* __restrict__ deg) {
  int e = blockIdx.x * 256 + threadIdx.x;
  if (e >= kE) return;
  int s = t[3*e], r = t[3*e+1], o = t[3*e+2];
  atomicAdd(&deg[s * kNRel + r], 1);              // norm for  out[s] += f[o]@W[r]
  atomicAdd(&deg[o * kNRel + kR0 + r], 1);        // norm for  out[o] += f[s]@W[r+8]
}

__global__ void k_scan1(const int* __restrict__ deg, int* __restrict__ rp,
                        int* __restrict__ blksum) {
  __shared__ int s[256];
  int tid = threadIdx.x;
  int base = blockIdx.x * kScanBlk + tid * 4;
  int v0 = 0, v1 = 0, v2 = 0, v3 = 0;
  if (base + 3 < kRows) {
    v0 = deg[base]; v1 = deg[base+1]; v2 = deg[base+2]; v3 = deg[base+3];
  } else {
    if (base     < kRows) v0 = deg[base];
    if (base + 1 < kRows) v1 = deg[base+1];
    if (base + 2 < kRows) v2 = deg[base+2];
  }
  int t0 = v0, t1 = t0 + v1, t2 = t1 + v2, t3 = t2 + v3;
  s[tid] = t3;
  __syncthreads();
  for (int off = 1; off < 256; off <<= 1) {
    int x = 0;
    if (tid >= off) x = s[tid - off];
    __syncthreads();
    s[tid] += x;
    __syncthreads();
  }
  int excl = tid ? s[tid-1] : 0;
  if (base     < kRows) rp[base]   = excl;
  if (base + 1 < kRows) rp[base+1] = excl + t0;
  if (base + 2 < kRows) rp[base+2] = excl + t1;
  if (base + 3 < kRows) rp[base+3] = excl + t2;
  if (tid == 255) blksum[blockIdx.x] = s[255];
}

__global__ void k_scan2(int* __restrict__ blksum) {
  __shared__ int s[512];
  int tid = threadIdx.x;
  s[tid] = (tid < kNScanBlk) ? blksum[tid] : 0;
  __syncthreads();
  for (int off = 1; off < 512; off <<= 1) {
    int x = 0;
    if (tid >= off) x = s[tid - off];
    __syncthreads();
    s[tid] += x;
    __syncthreads();
  }
  if (tid < kNScanBlk) blksum[tid] = tid ? s[tid-1] : 0;
}

__global__ void k_scan3(int* __restrict__ rp, const int* __restrict__ blksum) {
  int i = blockIdx.x * 256 + threadIdx.x;
  if (i < kRows)       rp[i] += blksum[i >> 10];
  else if (i == kRows) rp[i]  = kMsgs;
}

__global__ void k_scatter(const int* __restrict__ t, const int* __restrict__ rp,
                          int* __restrict__ cursor, int* __restrict__ col) {
  int m = blockIdx.x * 256 + threadIdx.x;
  if (m >= kMsgs) return;
  int e = (m < kE) ? m : m - kE;
  int s = t[3*e], r = t[3*e+1], o = t[3*e+2];
  int rr, tn, sn;
  if (m < kE) { rr = r;        tn = s; sn = o; }
  else        { rr = kR0 + r;  tn = o; sn = s; }
  int idx = tn * kNRel + rr;
  int pos = rp[idx] + atomicAdd(&cursor[idx], 1);
  col[pos] = (rr << 16) | sn;          // node ids < 30000 fit in 16 bits
}

#define FMA4(A, S, G) \
  A.x += (S) * G.x; A.y += (S) * G.y; A.z += (S) * G.z; A.w += (S) * G.w;

__global__ __launch_bounds__(512, 4)
void k_out(const int* __restrict__ rp, const int* __restrict__ col,
           const float* __restrict__ feat, const float* __restrict__ bases,
           const float* __restrict__ comps, const float* __restrict__ bias,
           float* __restrict__ out) {
  constexpr int TN = 8;
  __shared__ float aggb[TN][kNB * kIN];          // 64 KB (reused as reduce buffer)
  __shared__ float cvb[TN][kNRel][kNB];          // 4 KB premultiplied comps*1/deg
  __shared__ float comps_s[(2*kR0 + 1) * kNB];   // 136 floats
  int tid  = threadIdx.x;
  int wv   = tid >> 6;        // wave = local node (stage1) = k-group (stage2)
  int lane = tid & 63;
  int node0 = blockIdx.x * TN;
  int node  = node0 + wv;

  if (tid < (2*kR0 + 1) * kNB) comps_s[tid] = comps[tid];
  __syncthreads();

  // per-(node, rel) coefficients: cvb[wv][r][b] = comps[r,b] / deg_r(node)
  if (lane < kNRel) {
    int idx = node * kNRel + lane;
    int d   = rp[idx + 1] - rp[idx];
    float val = d > 0 ? 1.0f / (float)d : 0.0f;
#pragma unroll
    for (int b = 0; b < kNB; ++b)
      cvb[wv][lane][b] = comps_s[lane * kNB + b] * val;
  }
  int e0 = rp[node * kNRel];
  int e1 = rp[node * kNRel + kNRel];
  __syncthreads();

  // ---- stage 1: gather + combine into aggb[wv][b*256 + ch] ----
  {
    float4 f = *reinterpret_cast<const float4*>(feat + (size_t)node * kIN + lane * 4);
    float4 a[kNB];
#pragma unroll
    for (int b = 0; b < kNB; ++b) {           // self-loop (relation 16, val = 1)
      float cc = comps_s[2*kR0*kNB + b];
      a[b].x = cc * f.x; a[b].y = cc * f.y; a[b].z = cc * f.z; a[b].w = cc * f.w;
    }
#pragma unroll 2
    for (int e = e0; e < e1; ++e) {
      int c  = col[e];                         // uniform across wave
      int r  = c >> 16;
      int sn = c & 0xFFFF;
      float4 g = *reinterpret_cast<const float4*>(feat + (size_t)sn * kIN + lane * 4);
      const float4* cv = reinterpret_cast<const float4*>(cvb[wv][r]);
      float4 c0 = cv[0], c1 = cv[1];
      FMA4(a[0], c0.x, g) FMA4(a[1], c0.y, g) FMA4(a[2], c0.z, g) FMA4(a[3], c0.w, g)
      FMA4(a[4], c1.x, g) FMA4(a[5], c1.y, g) FMA4(a[6], c1.z, g) FMA4(a[7], c1.w, g)
    }
#pragma unroll
    for (int b = 0; b < kNB; ++b)
      *reinterpret_cast<float4*>(&aggb[wv][b * kIN + lane * 4]) = a[b];
  }
  __syncthreads();

  // ---- stage 2: out_tile = aggb[8][2048] @ basesFlat[2048][256], 8-way k-split ----
  // k-group wv covers k in [wv*256, wv*256+256)  (== basis block b = wv)
  float4 s2[TN];
#pragma unroll
  for (int n = 0; n < TN; ++n) s2[n] = make_float4(0.f, 0.f, 0.f, 0.f);
  {
    int o0 = lane * 4;
    int k0 = wv * 256;
#pragma unroll 2
    for (int k = k0; k < k0 + 256; k += 4) {
      const float* bp = bases + (size_t)k * kOUT + o0;
      float4 b0 = *reinterpret_cast<const float4*>(bp);
      float4 b1 = *reinterpret_cast<const float4*>(bp + kOUT);
      float4 b2 = *reinterpret_cast<const float4*>(bp + 2 * kOUT);
      float4 b3 = *reinterpret_cast<const float4*>(bp + 3 * kOUT);
#pragma unroll
      for (int n = 0; n < TN; ++n) {
        float4 av = *reinterpret_cast<const float4*>(&aggb[n][k]);   // LDS broadcast
        s2[n].x += av.x * b0.x + av.y * b1.x + av.z * b2.x + av.w * b3.x;
        s2[n].y += av.x * b0.y + av.y * b1.y + av.z * b2.y + av.w * b3.y;
        s2[n].z += av.x * b0.z + av.y * b1.z + av.z * b2.z + av.w * b3.z;
        s2[n].w += av.x * b0.w + av.y * b1.w + av.z * b2.w + av.w * b3.w;
      }
    }
  }
  __syncthreads();                 // all reads of aggb done; reuse it for reduction
  {
    int o0 = lane * 4;
    float* red = &aggb[0][0];      // [8 groups][8 nodes][256] = 16384 floats = 64 KB
#pragma unroll
    for (int n = 0; n < TN; ++n)
      *reinterpret_cast<float4*>(&red[(size_t)(wv * TN + n) * kOUT + o0]) = s2[n];
  }
  __syncthreads();
  {
    int i4 = tid * 4;              // 512 threads x 4 = 2048 = TN*256 outputs
    int n  = i4 >> 8;
    int oo = i4 & 255;
    const float* red = &aggb[0][0];
    float4 r = *reinterpret_cast<const float4*>(&bias[oo]);
#pragma unroll
    for (int g = 0; g < 8; ++g) {
      float4 p = *reinterpret_cast<const float4*>(&red[(size_t)(g * TN + n) * kOUT + oo]);
      r.x += p.x; r.y += p.y; r.z += p.z; r.w += p.w;
    }
    *reinterpret_cast<float4*>(&out[(size_t)(node0 + n) * kOUT + oo]) = r;
  }
}

extern "C" void kernel_launch(void* const* d_in, const int* in_sizes, int n_in,
                              void* d_out, int out_size, void* d_ws, size_t ws_size,
                              hipStream_t stream) {
  const int*   triples = (const int*)  d_in[0];
  const float* feat    = (const float*)d_in[1];
  const float* bases   = (const float*)d_in[2];
  const float* comps   = (const float*)d_in[3];
  const float* bias    = (const float*)d_in[4];
  float* out = (float*)d_out;

  int* ws_i   = (int*)d_ws;
  int* deg    = ws_i;                    // 480000 ints (also scatter cursor)
  int* rp     = deg + kRows;             // 480001 ints
  int* col    = rp + kRows + 1;          // 600000 ints
  int* blksum = col + kMsgs;             // 469 ints        total ~6.2 MB

  hipMemsetAsync(deg, 0, kRows * sizeof(int), stream);
  k_count <<<(kE + 255) / 256,   256, 0, stream>>>(triples, deg);
  k_scan1 <<<kNScanBlk,          256, 0, stream>>>(deg, rp, blksum);
  k_scan2 <<<1,                  512, 0, stream>>>(blksum);
  k_scan3 <<<(kRows + 256) / 256,256, 0, stream>>>(rp, blksum);
  hipMemsetAsync(deg, 0, kRows * sizeof(int), stream);   // reuse deg as cursor
  k_scatter<<<(kMsgs + 255) / 256, 256, 0, stream>>>(triples, rp, deg, col);
  k_out   <<<kN / 8,             512, 0, stream>>>(rp, col, feat, bases, comps, bias, out);
}

// Round 3
// 360.871 us; speedup vs baseline: 1.7350x; 1.7350x over previous
//
#include <hip/hip_runtime.h>

// R-GCN basis-decomposed layer, MFMA stage-2.
// out[n] = bias + f[n]@W[16] + sum_{r<16} (1/deg_r(n)) * (sum_{nb} f[nb]) @ W[r]
// W[r] = sum_b comps[r,b]*bases[b]  =>  out = aggb[30000,2048] @ basesFlat[2048,256] + bias
// aggb rows built per-block in LDS (f32 accum -> bf16), stage 2 = mfma_f32_16x16x32_bf16
// against pre-transposed bf16 Bt[256][2048].
//
// ws: Bt (1 MB) | deg/cursor[480000] | rp[480001] | col[600000] | blksum[469]  (~7.3 MB)

namespace {
constexpr int kN     = 30000;
constexpr int kR0    = 8;
constexpr int kNRel  = 16;
constexpr int kIN    = 256;
constexpr int kOUT   = 256;
constexpr int kE     = 300000;
constexpr int kNB    = 8;
constexpr int kKT    = kNB * kIN;          // 2048
constexpr int kRows  = kN * kNRel;         // 480000
constexpr int kMsgs  = 2 * kE;             // 600000
constexpr int kScanBlk  = 1024;
constexpr int kNScanBlk = (kRows + kScanBlk - 1) / kScanBlk;   // 469
constexpr int kTN    = 16;                 // nodes per k_out block
}

typedef __bf16 bf16x8 __attribute__((ext_vector_type(8)));
typedef float  f32x4  __attribute__((ext_vector_type(4)));

static __device__ __forceinline__ ushort f2bf(float x) {
  unsigned u = __float_as_uint(x);
  u += 0x7FFF + ((u >> 16) & 1);           // round-to-nearest-even
  return (ushort)(u >> 16);
}

__global__ void k_count(const int* __restrict__ t, int* __restrict__ deg) {
  int e = blockIdx.x * 256 + threadIdx.x;
  if (e >= kE) return;
  int s = t[3*e], r = t[3*e+1], o = t[3*e+2];
  atomicAdd(&deg[s * kNRel + r], 1);
  atomicAdd(&deg[o * kNRel + kR0 + r], 1);
}

__global__ void k_scan1(const int* __restrict__ deg, int* __restrict__ rp,
                        int* __restrict__ blksum) {
  __shared__ int s[256];
  int tid = threadIdx.x;
  int base = blockIdx.x * kScanBlk + tid * 4;
  int v0 = 0, v1 = 0, v2 = 0, v3 = 0;
  if (base + 3 < kRows) {
    v0 = deg[base]; v1 = deg[base+1]; v2 = deg[base+2]; v3 = deg[base+3];
  } else {
    if (base     < kRows) v0 = deg[base];
    if (base + 1 < kRows) v1 = deg[base+1];
    if (base + 2 < kRows) v2 = deg[base+2];
  }
  int t0 = v0, t1 = t0 + v1, t2 = t1 + v2, t3 = t2 + v3;
  s[tid] = t3;
  __syncthreads();
  for (int off = 1; off < 256; off <<= 1) {
    int x = 0;
    if (tid >= off) x = s[tid - off];
    __syncthreads();
    s[tid] += x;
    __syncthreads();
  }
  int excl = tid ? s[tid-1] : 0;
  if (base     < kRows) rp[base]   = excl;
  if (base + 1 < kRows) rp[base+1] = excl + t0;
  if (base + 2 < kRows) rp[base+2] = excl + t1;
  if (base + 3 < kRows) rp[base+3] = excl + t2;
  if (tid == 255) blksum[blockIdx.x] = s[255];
}

__global__ void k_scan2(int* __restrict__ blksum) {
  __shared__ int s[512];
  int tid = threadIdx.x;
  s[tid] = (tid < kNScanBlk) ? blksum[tid] : 0;
  __syncthreads();
  for (int off = 1; off < 512; off <<= 1) {
    int x = 0;
    if (tid >= off) x = s[tid - off];
    __syncthreads();
    s[tid] += x;
    __syncthreads();
  }
  if (tid < kNScanBlk) blksum[tid] = tid ? s[tid-1] : 0;
}

__global__ void k_scan3(int* __restrict__ rp, const int* __restrict__ blksum) {
  int i = blockIdx.x * 256 + threadIdx.x;
  if (i < kRows)       rp[i] += blksum[i >> 10];
  else if (i == kRows) rp[i]  = kMsgs;
}

__global__ void k_scatter(const int* __restrict__ t, const int* __restrict__ rp,
                          int* __restrict__ cursor, int* __restrict__ col) {
  int m = blockIdx.x * 256 + threadIdx.x;
  if (m >= kMsgs) return;
  int e = (m < kE) ? m : m - kE;
  int s = t[3*e], r = t[3*e+1], o = t[3*e+2];
  int rr, tn, sn;
  if (m < kE) { rr = r;        tn = s; sn = o; }
  else        { rr = kR0 + r;  tn = o; sn = s; }
  int idx = tn * kNRel + rr;
  int pos = rp[idx] + atomicAdd(&cursor[idx], 1);
  col[pos] = (rr << 16) | sn;
}

// bases[2048][256] f32 -> Bt[256][2048] bf16 (contiguous in k per output column)
__global__ void k_bt(const float* __restrict__ bases, ushort* __restrict__ Bt) {
  __shared__ float tile[16][256];
  int b = blockIdx.x;            // k-block [b*16, b*16+16)
  int t = threadIdx.x;           // 256
#pragma unroll
  for (int kk = 0; kk < 16; ++kk)
    tile[kk][t] = bases[(size_t)(b * 16 + kk) * kOUT + t];
  __syncthreads();
  ushort4 p[4];
#pragma unroll
  for (int q = 0; q < 4; ++q) {
    p[q].x = f2bf(tile[q*4+0][t]); p[q].y = f2bf(tile[q*4+1][t]);
    p[q].z = f2bf(tile[q*4+2][t]); p[q].w = f2bf(tile[q*4+3][t]);
  }
  ushort* dst = Bt + (size_t)t * kKT + b * 16;
#pragma unroll
  for (int q = 0; q < 4; ++q)
    *reinterpret_cast<ushort4*>(dst + q * 4) = p[q];
}

#define FMA4(A, S, G) \
  A.x += (S) * G.x; A.y += (S) * G.y; A.z += (S) * G.z; A.w += (S) * G.w;

__global__ __launch_bounds__(1024, 8)
void k_out(const int* __restrict__ rp, const int* __restrict__ col,
           const float* __restrict__ feat, const ushort* __restrict__ Bt,
           const float* __restrict__ comps, const float* __restrict__ bias,
           float* __restrict__ out) {
  __shared__ ushort aggs[kTN * kKT];             // 64 KB bf16 A-tile, XOR-swizzled rows
  __shared__ float  cvb[kTN][kNRel][kNB];        // 8 KB premultiplied comps/deg
  __shared__ float  comps_s[(2*kR0 + 1) * kNB];  // 136 floats
  int tid  = threadIdx.x;
  int wv   = tid >> 6;         // wave 0..15: stage1 = local node, stage2 = n-tile
  int lane = tid & 63;
  int node0 = blockIdx.x * kTN;
  int node  = node0 + wv;

  if (tid < (2*kR0 + 1) * kNB) comps_s[tid] = comps[tid];
  __syncthreads();

  if (lane < kNRel) {
    int idx = node * kNRel + lane;
    int d   = rp[idx + 1] - rp[idx];
    float val = d > 0 ? 1.0f / (float)d : 0.0f;
#pragma unroll
    for (int b = 0; b < kNB; ++b)
      cvb[wv][lane][b] = comps_s[lane * kNB + b] * val;
  }
  int e0 = rp[node * kNRel];
  int e1 = rp[node * kNRel + kNRel];

  // ---- stage 1: gather + combine (f32), write bf16 row to LDS (swizzled) ----
  {
    float4 f = *reinterpret_cast<const float4*>(feat + (size_t)node * kIN + lane * 4);
    float4 a[kNB];
#pragma unroll
    for (int b = 0; b < kNB; ++b) {              // self-loop (relation 16, val=1)
      float cc = comps_s[2*kR0*kNB + b];
      a[b].x = cc * f.x; a[b].y = cc * f.y; a[b].z = cc * f.z; a[b].w = cc * f.w;
    }
#pragma unroll 2
    for (int e = e0; e < e1; ++e) {
      int c  = col[e];                           // wave-uniform
      int r  = c >> 16;
      int sn = c & 0xFFFF;
      float4 g = *reinterpret_cast<const float4*>(feat + (size_t)sn * kIN + lane * 4);
      const float4* cv = reinterpret_cast<const float4*>(cvb[wv][r]);
      float4 c0 = cv[0], c1 = cv[1];
      FMA4(a[0], c0.x, g) FMA4(a[1], c0.y, g) FMA4(a[2], c0.z, g) FMA4(a[3], c0.w, g)
      FMA4(a[4], c1.x, g) FMA4(a[5], c1.y, g) FMA4(a[6], c1.z, g) FMA4(a[7], c1.w, g)
    }
    int xr = (wv & 7) << 4;                      // row XOR swizzle (T2)
#pragma unroll
    for (int b = 0; b < kNB; ++b) {
      ushort4 p;
      p.x = f2bf(a[b].x); p.y = f2bf(a[b].y); p.z = f2bf(a[b].z); p.w = f2bf(a[b].w);
      int byteoff = wv * 4096 + ((b * 512 + lane * 8) ^ xr);
      *reinterpret_cast<ushort4*>(reinterpret_cast<char*>(aggs) + byteoff) = p;
    }
  }
  __syncthreads();

  // ---- stage 2: wave wv computes D[16 nodes][cols wv*16..+16) via 64 MFMAs ----
  {
    int n = lane & 15;           // B col / D col
    int g = lane >> 4;           // k-group
    int m = n;                   // A row (lane&15 mapping, same as B col)
    float bi = bias[wv * 16 + n];
    const char* btrow = reinterpret_cast<const char*>(Bt + (size_t)(wv * 16 + n) * kKT);
    const char* abase = reinterpret_cast<const char*>(aggs) + m * 4096;
    int axor = (m & 7) << 4;
    f32x4 acc = {0.f, 0.f, 0.f, 0.f};
#pragma unroll 4
    for (int ks = 0; ks < kKT / 32; ++ks) {
      int kb = ks * 64 + g * 16;                 // byte offset of this lane's 8 bf16
      bf16x8 af = *reinterpret_cast<const bf16x8*>(abase + (kb ^ axor));
      bf16x8 bf = *reinterpret_cast<const bf16x8*>(btrow + kb);
      acc = __builtin_amdgcn_mfma_f32_16x16x32_bf16(af, bf, acc, 0, 0, 0);
    }
#pragma unroll
    for (int j = 0; j < 4; ++j) {
      int row = g * 4 + j;                       // D row = (lane>>4)*4 + reg
      out[(size_t)(node0 + row) * kOUT + wv * 16 + n] = acc[j] + bi;
    }
  }
}

extern "C" void kernel_launch(void* const* d_in, const int* in_sizes, int n_in,
                              void* d_out, int out_size, void* d_ws, size_t ws_size,
                              hipStream_t stream) {
  const int*   triples = (const int*)  d_in[0];
  const float* feat    = (const float*)d_in[1];
  const float* bases   = (const float*)d_in[2];
  const float* comps   = (const float*)d_in[3];
  const float* bias    = (const float*)d_in[4];
  float* out = (float*)d_out;

  ushort* Bt  = (ushort*)d_ws;                   // 2048*256 bf16 = 1 MB
  int* deg    = (int*)d_ws + (kKT * kOUT / 2);   // 480000 ints (also cursor)
  int* rp     = deg + kRows;                     // 480001
  int* col    = rp + kRows + 1;                  // 600000
  int* blksum = col + kMsgs;                     // 469

  k_bt    <<<kKT / 16,            256, 0, stream>>>(bases, Bt);
  hipMemsetAsync(deg, 0, kRows * sizeof(int), stream);
  k_count <<<(kE + 255) / 256,    256, 0, stream>>>(triples, deg);
  k_scan1 <<<kNScanBlk,           256, 0, stream>>>(deg, rp, blksum);
  k_scan2 <<<1,                   512, 0, stream>>>(blksum);
  k_scan3 <<<(kRows + 256) / 256, 256, 0, stream>>>(rp, blksum);
  hipMemsetAsync(deg, 0, kRows * sizeof(int), stream);
  k_scatter<<<(kMsgs + 255) / 256, 256, 0, stream>>>(triples, rp, deg, col);
  k_out   <<<kN / kTN,           1024, 0, stream>>>(rp, col, feat, Bt, comps, bias, out);
}

// Round 4
// 346.859 us; speedup vs baseline: 1.8051x; 1.0404x over previous
//
#include <hip/hip_runtime.h>

// R-GCN basis-decomposed layer, MFMA stage-2, pipelined bf16 gather stage-1.
// out[n] = bias + f[n]@W[16] + sum_{r<16} (1/deg_r(n)) * (sum_{nb} f[nb]) @ W[r]
// W[r] = sum_b comps[r,b]*bases[b]  =>  out = aggb[30000,2048] @ basesFlat[2048,256] + bias
//
// k_out blocks: 512 thr / 8 waves / 16 nodes. Stage 1: wave w gathers nodes 2w,2w+1
// (bf16 features, 4-deep software pipeline, zero-coeff r=16 tail padding), combines
// into bf16 LDS A-tile. Stage 2: wave w runs n-tiles {w, w+8} with mfma 16x16x32 bf16
// against pre-transposed bf16 Bt[256][2048].
//
// ws (~22.7 MB): featbf (15.36 MB) | Bt (1 MB) | deg/cursor | rp | col | blksum

namespace {
constexpr int kN     = 30000;
constexpr int kR0    = 8;
constexpr int kNRel  = 16;
constexpr int kIN    = 256;
constexpr int kOUT   = 256;
constexpr int kE     = 300000;
constexpr int kNB    = 8;
constexpr int kKT    = kNB * kIN;          // 2048
constexpr int kRows  = kN * kNRel;         // 480000
constexpr int kMsgs  = 2 * kE;             // 600000
constexpr int kScanBlk  = 1024;
constexpr int kNScanBlk = (kRows + kScanBlk - 1) / kScanBlk;   // 469
constexpr int kTN    = 16;                 // nodes per k_out block
}

typedef __bf16 bf16x8 __attribute__((ext_vector_type(8)));
typedef float  f32x4  __attribute__((ext_vector_type(4)));

static __device__ __forceinline__ ushort f2bf(float x) {
  unsigned u = __float_as_uint(x);
  u += 0x7FFF + ((u >> 16) & 1);           // round-to-nearest-even
  return (ushort)(u >> 16);
}

__global__ void k_fbf(const float* __restrict__ f, ushort* __restrict__ fb) {
  int i = blockIdx.x * 256 + threadIdx.x;      // one float4 per thread
  if (i >= kN * kIN / 4) return;
  float4 v = reinterpret_cast<const float4*>(f)[i];
  ushort4 p;
  p.x = f2bf(v.x); p.y = f2bf(v.y); p.z = f2bf(v.z); p.w = f2bf(v.w);
  reinterpret_cast<ushort4*>(fb)[i] = p;
}

__global__ void k_count(const int* __restrict__ t, int* __restrict__ deg) {
  int e = blockIdx.x * 256 + threadIdx.x;
  if (e >= kE) return;
  int s = t[3*e], r = t[3*e+1], o = t[3*e+2];
  atomicAdd(&deg[s * kNRel + r], 1);
  atomicAdd(&deg[o * kNRel + kR0 + r], 1);
}

__global__ void k_scan1(const int* __restrict__ deg, int* __restrict__ rp,
                        int* __restrict__ blksum) {
  __shared__ int s[256];
  int tid = threadIdx.x;
  int base = blockIdx.x * kScanBlk + tid * 4;
  int v0 = 0, v1 = 0, v2 = 0, v3 = 0;
  if (base + 3 < kRows) {
    v0 = deg[base]; v1 = deg[base+1]; v2 = deg[base+2]; v3 = deg[base+3];
  } else {
    if (base     < kRows) v0 = deg[base];
    if (base + 1 < kRows) v1 = deg[base+1];
    if (base + 2 < kRows) v2 = deg[base+2];
  }
  int t0 = v0, t1 = t0 + v1, t2 = t1 + v2, t3 = t2 + v3;
  s[tid] = t3;
  __syncthreads();
  for (int off = 1; off < 256; off <<= 1) {
    int x = 0;
    if (tid >= off) x = s[tid - off];
    __syncthreads();
    s[tid] += x;
    __syncthreads();
  }
  int excl = tid ? s[tid-1] : 0;
  if (base     < kRows) rp[base]   = excl;
  if (base + 1 < kRows) rp[base+1] = excl + t0;
  if (base + 2 < kRows) rp[base+2] = excl + t1;
  if (base + 3 < kRows) rp[base+3] = excl + t2;
  if (tid == 255) blksum[blockIdx.x] = s[255];
}

__global__ void k_scan2(int* __restrict__ blksum) {
  __shared__ int s[512];
  int tid = threadIdx.x;
  s[tid] = (tid < kNScanBlk) ? blksum[tid] : 0;
  __syncthreads();
  for (int off = 1; off < 512; off <<= 1) {
    int x = 0;
    if (tid >= off) x = s[tid - off];
    __syncthreads();
    s[tid] += x;
    __syncthreads();
  }
  if (tid < kNScanBlk) blksum[tid] = tid ? s[tid-1] : 0;
}

__global__ void k_scan3(int* __restrict__ rp, const int* __restrict__ blksum) {
  int i = blockIdx.x * 256 + threadIdx.x;
  if (i < kRows)       rp[i] += blksum[i >> 10];
  else if (i == kRows) rp[i]  = kMsgs;
}

__global__ void k_scatter(const int* __restrict__ t, const int* __restrict__ rp,
                          int* __restrict__ cursor, int* __restrict__ col) {
  int m = blockIdx.x * 256 + threadIdx.x;
  if (m >= kMsgs) return;
  int e = (m < kE) ? m : m - kE;
  int s = t[3*e], r = t[3*e+1], o = t[3*e+2];
  int rr, tn, sn;
  if (m < kE) { rr = r;        tn = s; sn = o; }
  else        { rr = kR0 + r;  tn = o; sn = s; }
  int idx = tn * kNRel + rr;
  int pos = rp[idx] + atomicAdd(&cursor[idx], 1);
  col[pos] = (rr << 16) | sn;
}

// bases[2048][256] f32 -> Bt[256][2048] bf16 (contiguous in k per output column)
__global__ void k_bt(const float* __restrict__ bases, ushort* __restrict__ Bt) {
  __shared__ float tile[16][256];
  int b = blockIdx.x;            // k-block [b*16, b*16+16)
  int t = threadIdx.x;           // 256
#pragma unroll
  for (int kk = 0; kk < 16; ++kk)
    tile[kk][t] = bases[(size_t)(b * 16 + kk) * kOUT + t];
  __syncthreads();
  ushort4 p[4];
#pragma unroll
  for (int q = 0; q < 4; ++q) {
    p[q].x = f2bf(tile[q*4+0][t]); p[q].y = f2bf(tile[q*4+1][t]);
    p[q].z = f2bf(tile[q*4+2][t]); p[q].w = f2bf(tile[q*4+3][t]);
  }
  ushort* dst = Bt + (size_t)t * kKT + b * 16;
#pragma unroll
  for (int q = 0; q < 4; ++q)
    *reinterpret_cast<ushort4*>(dst + q * 4) = p[q];
}

#define FMA4(A, S, G) \
  A.x += (S) * G.x; A.y += (S) * G.y; A.z += (S) * G.z; A.w += (S) * G.w;

__global__ __launch_bounds__(512, 4)
void k_out(const int* __restrict__ rp, const int* __restrict__ col,
           const float* __restrict__ feat, const ushort* __restrict__ featbf,
           const ushort* __restrict__ Bt, const float* __restrict__ comps,
           const float* __restrict__ bias, float* __restrict__ out) {
  __shared__ ushort aggs[kTN * kKT];          // 64 KB bf16 A-tile, XOR-swizzled rows
  __shared__ float  cvb[kTN][17][kNB];        // 8.5 KB: comps[r,b]/deg (row 16 = zeros)
  int tid  = threadIdx.x;
  int wv   = tid >> 6;          // wave 0..7
  int lane = tid & 63;
  int node0 = blockIdx.x * kTN;

  // per-(node, rel) coefficients; rel slot 16 is the zero pad target
  for (int q = tid; q < kTN * 17; q += 512) {
    int nl = q / 17, rl = q - nl * 17;
    float val = 0.f;
    if (rl < kNRel) {
      int idx = (node0 + nl) * kNRel + rl;
      int d = rp[idx + 1] - rp[idx];
      val = d > 0 ? 1.0f / (float)d : 0.f;
    }
#pragma unroll
    for (int b = 0; b < kNB; ++b)
      cvb[nl][rl][b] = comps[rl * kNB + b] * val;
  }
  __syncthreads();

  // ---- stage 1: each wave builds 2 node rows (4-deep pipelined bf16 gather) ----
  for (int half = 0; half < 2; ++half) {
    int nl   = (wv << 1) | half;
    int node = node0 + nl;
    int e0 = rp[node * kNRel];
    int e1 = rp[node * kNRel + kNRel];

    float4 f = *reinterpret_cast<const float4*>(feat + (size_t)node * kIN + lane * 4);
    float4 acc[kNB];
#pragma unroll
    for (int b = 0; b < kNB; ++b) {           // self-loop (relation 16, val = 1)
      float cs = comps[2*kR0*kNB + b];
      acc[b].x = cs * f.x; acc[b].y = cs * f.y; acc[b].z = cs * f.z; acc[b].w = cs * f.w;
    }

    const float4* cvr = reinterpret_cast<const float4*>(&cvb[nl][0][0]);
    const int pad = (16 << 16) | node0;       // rel 16 -> zero coeffs
    int cc[4];
#pragma unroll
    for (int j = 0; j < 4; ++j) {
      int ee = e0 + j;
      int v  = col[ee < kMsgs ? ee : kMsgs - 1];
      cc[j] = ee < e1 ? v : pad;
    }
    for (int e = e0; e < e1; e += 4) {
      uint2 g[4];
#pragma unroll
      for (int j = 0; j < 4; ++j) {           // 4 independent 8B gathers in flight
        int sn = cc[j] & 0xFFFF;
        g[j] = *reinterpret_cast<const uint2*>(featbf + (size_t)sn * kIN + lane * 4);
      }
      int rr[4];
#pragma unroll
      for (int j = 0; j < 4; ++j) rr[j] = cc[j] >> 16;
#pragma unroll
      for (int j = 0; j < 4; ++j) {           // prefetch next chunk's col entries
        int ee = e + 4 + j;
        int v  = col[ee < kMsgs ? ee : kMsgs - 1];
        cc[j] = ee < e1 ? v : pad;
      }
#pragma unroll
      for (int j = 0; j < 4; ++j) {
        float4 c0 = cvr[rr[j] * 2];
        float4 c1 = cvr[rr[j] * 2 + 1];
        float4 gg;
        gg.x = __uint_as_float(g[j].x << 16);
        gg.y = __uint_as_float(g[j].x & 0xFFFF0000u);
        gg.z = __uint_as_float(g[j].y << 16);
        gg.w = __uint_as_float(g[j].y & 0xFFFF0000u);
        FMA4(acc[0], c0.x, gg) FMA4(acc[1], c0.y, gg)
        FMA4(acc[2], c0.z, gg) FMA4(acc[3], c0.w, gg)
        FMA4(acc[4], c1.x, gg) FMA4(acc[5], c1.y, gg)
        FMA4(acc[6], c1.z, gg) FMA4(acc[7], c1.w, gg)
      }
    }
    int xr = (nl & 7) << 4;                   // row XOR swizzle
#pragma unroll
    for (int b = 0; b < kNB; ++b) {
      ushort4 p;
      p.x = f2bf(acc[b].x); p.y = f2bf(acc[b].y);
      p.z = f2bf(acc[b].z); p.w = f2bf(acc[b].w);
      int byteoff = nl * 4096 + ((b * 512 + lane * 8) ^ xr);
      *reinterpret_cast<ushort4*>(reinterpret_cast<char*>(aggs) + byteoff) = p;
    }
  }
  __syncthreads();

  // ---- stage 2: wave wv runs n-tiles {wv, wv+8}, 64 MFMAs each ----
  {
    int n  = lane & 15;          // B col / D col; also A row
    int g4 = lane >> 4;          // k-group
    const char* abase = reinterpret_cast<const char*>(aggs) + n * 4096;
    int axor = (n & 7) << 4;
#pragma unroll
    for (int t = 0; t < 2; ++t) {
      int ntile = wv + t * 8;
      float bi = bias[ntile * 16 + n];
      const char* btrow = reinterpret_cast<const char*>(Bt + (size_t)(ntile * 16 + n) * kKT);
      f32x4 acc = {0.f, 0.f, 0.f, 0.f};
#pragma unroll 4
      for (int ks = 0; ks < kKT / 32; ++ks) {
        int kb = ks * 64 + g4 * 16;
        bf16x8 af = *reinterpret_cast<const bf16x8*>(abase + (kb ^ axor));
        bf16x8 bf = *reinterpret_cast<const bf16x8*>(btrow + kb);
        acc = __builtin_amdgcn_mfma_f32_16x16x32_bf16(af, bf, acc, 0, 0, 0);
      }
#pragma unroll
      for (int j = 0; j < 4; ++j) {
        int row = g4 * 4 + j;
        out[(size_t)(node0 + row) * kOUT + ntile * 16 + n] = acc[j] + bi;
      }
    }
  }
}

extern "C" void kernel_launch(void* const* d_in, const int* in_sizes, int n_in,
                              void* d_out, int out_size, void* d_ws, size_t ws_size,
                              hipStream_t stream) {
  const int*   triples = (const int*)  d_in[0];
  const float* feat    = (const float*)d_in[1];
  const float* bases   = (const float*)d_in[2];
  const float* comps   = (const float*)d_in[3];
  const float* bias    = (const float*)d_in[4];
  float* out = (float*)d_out;

  ushort* featbf = (ushort*)d_ws;                      // 30000*256 bf16 = 15.36 MB
  ushort* Bt     = featbf + (size_t)kN * kIN;          // 2048*256 bf16 = 1 MB
  int* deg    = (int*)(Bt + (size_t)kKT * kOUT / 8 * 8 + 0) + 0;  // placed after Bt
  deg         = (int*)((char*)(Bt + (size_t)kKT * kOUT));
  int* rp     = deg + kRows;                           // 480001
  int* col    = rp + kRows + 1;                        // 600000
  int* blksum = col + kMsgs;                           // 469

  k_fbf   <<<(kN * kIN / 4 + 255) / 256, 256, 0, stream>>>(feat, featbf);
  k_bt    <<<kKT / 16,            256, 0, stream>>>(bases, Bt);
  hipMemsetAsync(deg, 0, kRows * sizeof(int), stream);
  k_count <<<(kE + 255) / 256,    256, 0, stream>>>(triples, deg);
  k_scan1 <<<kNScanBlk,           256, 0, stream>>>(deg, rp, blksum);
  k_scan2 <<<1,                   512, 0, stream>>>(blksum);
  k_scan3 <<<(kRows + 256) / 256, 256, 0, stream>>>(rp, blksum);
  hipMemsetAsync(deg, 0, kRows * sizeof(int), stream);
  k_scatter<<<(kMsgs + 255) / 256, 256, 0, stream>>>(triples, rp, deg, col);
  k_out   <<<kN / kTN,            512, 0, stream>>>(rp, col, feat, featbf, Bt,
                                                    comps, bias, out);
}

// Round 5
// 191.983 us; speedup vs baseline: 3.2613x; 1.8067x over previous
//
#include <hip/hip_runtime.h>

// R-GCN basis-decomposed layer, fissioned:
//   k_agg1: 1 wave/node gather+combine -> aggb[30016][2048] bf16 (pre-swizzled rows)
//   k_gemm: out = aggb @ BtT via mfma 16x16x32 bf16, A/B staged with global_load_lds
// Fallback (small ws): round-4 fused kernel (swizzled-Bt reader).
//
// ws path A (~145.6 MB): featbf | Bt | aggb | deg | rp | col | blksum
// ws path B (~22.7 MB):  featbf | Bt | deg | rp | col | blksum

namespace {
constexpr int kN     = 30000;
constexpr int kR0    = 8;
constexpr int kNRel  = 16;
constexpr int kIN    = 256;
constexpr int kOUT   = 256;
constexpr int kE     = 300000;
constexpr int kNB    = 8;
constexpr int kKT    = kNB * kIN;          // 2048
constexpr int kRows  = kN * kNRel;         // 480000
constexpr int kMsgs  = 2 * kE;             // 600000
constexpr int kScanBlk  = 1024;
constexpr int kNScanBlk = (kRows + kScanBlk - 1) / kScanBlk;   // 469
constexpr int kBM    = 64;
constexpr int kMB    = (kN + kBM - 1) / kBM;   // 469 gemm blocks
constexpr int kMPad  = kMB * kBM;              // 30016 padded rows
constexpr int kTN    = 16;                 // fused-path nodes per block
}

typedef __bf16 bf16x8 __attribute__((ext_vector_type(8)));
typedef float  f32x4  __attribute__((ext_vector_type(4)));
typedef unsigned int u32;

static __device__ __forceinline__ ushort f2bf(float x) {
  unsigned u = __float_as_uint(x);
  u += 0x7FFF + ((u >> 16) & 1);           // round-to-nearest-even
  return (ushort)(u >> 16);
}

static __device__ __forceinline__ void gload16(const void* g, void* l) {
  __builtin_amdgcn_global_load_lds(
      (const __attribute__((address_space(1))) u32*)g,
      (__attribute__((address_space(3))) u32*)l, 16, 0, 0);
}

// ---------------- prep: bf16 feature copy, swizzled bf16 Bt ----------------

__global__ void k_fbf(const float* __restrict__ f, ushort* __restrict__ fb) {
  int i = blockIdx.x * 256 + threadIdx.x;
  if (i >= kN * kIN / 4) return;
  float4 v = reinterpret_cast<const float4*>(f)[i];
  ushort4 p;
  p.x = f2bf(v.x); p.y = f2bf(v.y); p.z = f2bf(v.z); p.w = f2bf(v.w);
  reinterpret_cast<ushort4*>(fb)[i] = p;
}

// bases[2048][256] f32 -> Bt rows: col-major [256 cols][2048 k] bf16, row bytes
// XOR-swizzled by ((col&7)<<4) so GEMM LDS frag reads are spread across banks.
__global__ void k_bt(const float* __restrict__ bases, ushort* __restrict__ Bt) {
  __shared__ float tile[16][256];
  int b = blockIdx.x;            // k-block [b*16, b*16+16)
  int t = threadIdx.x;           // 256 = col
#pragma unroll
  for (int kk = 0; kk < 16; ++kk)
    tile[kk][t] = bases[(size_t)(b * 16 + kk) * kOUT + t];
  __syncthreads();
  char* dst = (char*)Bt + (size_t)t * 4096;
  int xr = (t & 7) << 4;
#pragma unroll
  for (int q = 0; q < 4; ++q) {
    ushort4 p;
    p.x = f2bf(tile[q*4+0][t]); p.y = f2bf(tile[q*4+1][t]);
    p.z = f2bf(tile[q*4+2][t]); p.w = f2bf(tile[q*4+3][t]);
    *reinterpret_cast<ushort4*>(dst + ((b * 32 + q * 8) ^ xr)) = p;
  }
}

// ---------------- CSR build ----------------

__global__ void k_count(const int* __restrict__ t, int* __restrict__ deg) {
  int e = blockIdx.x * 256 + threadIdx.x;
  if (e >= kE) return;
  int s = t[3*e], r = t[3*e+1], o = t[3*e+2];
  atomicAdd(&deg[s * kNRel + r], 1);
  atomicAdd(&deg[o * kNRel + kR0 + r], 1);
}

__global__ void k_scan1(const int* __restrict__ deg, int* __restrict__ rp,
                        int* __restrict__ blksum) {
  __shared__ int s[256];
  int tid = threadIdx.x;
  int base = blockIdx.x * kScanBlk + tid * 4;
  int v0 = 0, v1 = 0, v2 = 0, v3 = 0;
  if (base + 3 < kRows) {
    v0 = deg[base]; v1 = deg[base+1]; v2 = deg[base+2]; v3 = deg[base+3];
  } else {
    if (base     < kRows) v0 = deg[base];
    if (base + 1 < kRows) v1 = deg[base+1];
    if (base + 2 < kRows) v2 = deg[base+2];
  }
  int t0 = v0, t1 = t0 + v1, t2 = t1 + v2, t3 = t2 + v3;
  s[tid] = t3;
  __syncthreads();
  for (int off = 1; off < 256; off <<= 1) {
    int x = 0;
    if (tid >= off) x = s[tid - off];
    __syncthreads();
    s[tid] += x;
    __syncthreads();
  }
  int excl = tid ? s[tid-1] : 0;
  if (base     < kRows) rp[base]   = excl;
  if (base + 1 < kRows) rp[base+1] = excl + t0;
  if (base + 2 < kRows) rp[base+2] = excl + t1;
  if (base + 3 < kRows) rp[base+3] = excl + t2;
  if (tid == 255) blksum[blockIdx.x] = s[255];
}

__global__ void k_scan2(int* __restrict__ blksum) {
  __shared__ int s[512];
  int tid = threadIdx.x;
  s[tid] = (tid < kNScanBlk) ? blksum[tid] : 0;
  __syncthreads();
  for (int off = 1; off < 512; off <<= 1) {
    int x = 0;
    if (tid >= off) x = s[tid - off];
    __syncthreads();
    s[tid] += x;
    __syncthreads();
  }
  if (tid < kNScanBlk) blksum[tid] = tid ? s[tid-1] : 0;
}

__global__ void k_scan3(int* __restrict__ rp, const int* __restrict__ blksum) {
  int i = blockIdx.x * 256 + threadIdx.x;
  if (i < kRows)       rp[i] += blksum[i >> 10];
  else if (i == kRows) rp[i]  = kMsgs;
}

__global__ void k_scatter(const int* __restrict__ t, const int* __restrict__ rp,
                          int* __restrict__ cursor, int* __restrict__ col) {
  int m = blockIdx.x * 256 + threadIdx.x;
  if (m >= kMsgs) return;
  int e = (m < kE) ? m : m - kE;
  int s = t[3*e], r = t[3*e+1], o = t[3*e+2];
  int rr, tn, sn;
  if (m < kE) { rr = r;        tn = s; sn = o; }
  else        { rr = kR0 + r;  tn = o; sn = s; }
  int idx = tn * kNRel + rr;
  int pos = rp[idx] + atomicAdd(&cursor[idx], 1);
  col[pos] = (rr << 16) | sn;
}

#define FMA4(A, S, G) \
  A.x += (S) * G.x; A.y += (S) * G.y; A.z += (S) * G.z; A.w += (S) * G.w;

// ---------------- path A stage 1: one wave per node ----------------

__global__ __launch_bounds__(256, 6)
void k_agg1(const int* __restrict__ rp, const int* __restrict__ col,
            const float* __restrict__ feat, const ushort* __restrict__ featbf,
            const float* __restrict__ comps, ushort* __restrict__ aggb) {
  __shared__ float cvb[4][17][kNB];     // per-wave coeff table, row 16 = zeros
  int wv   = threadIdx.x >> 6;
  int lane = threadIdx.x & 63;
  int node = blockIdx.x * 4 + wv;       // kN % 4 == 0

  if (lane < 17) {
    float val = 0.f;
    if (lane < kNRel) {
      int idx = node * kNRel + lane;
      int d = rp[idx + 1] - rp[idx];
      val = d > 0 ? 1.0f / (float)d : 0.f;
    }
#pragma unroll
    for (int b = 0; b < kNB; ++b)
      cvb[wv][lane][b] = comps[lane * kNB + b] * val;
  }
  __syncthreads();

  int e0 = rp[node * kNRel];
  int e1 = rp[node * kNRel + kNRel];

  float4 f = *reinterpret_cast<const float4*>(feat + (size_t)node * kIN + lane * 4);
  float4 acc[kNB];
#pragma unroll
  for (int b = 0; b < kNB; ++b) {       // self-loop (relation 16, val = 1)
    float cs = comps[2*kR0*kNB + b];
    acc[b].x = cs * f.x; acc[b].y = cs * f.y; acc[b].z = cs * f.z; acc[b].w = cs * f.w;
  }

  const float4* cvr = reinterpret_cast<const float4*>(&cvb[wv][0][0]);
  const int pad = (16 << 16);           // rel slot 16 -> zero coeffs
  int cc[4];
#pragma unroll
  for (int j = 0; j < 4; ++j) {
    int ee = e0 + j;
    int v  = col[ee < kMsgs ? ee : kMsgs - 1];
    cc[j] = ee < e1 ? v : pad;
  }
  for (int e = e0; e < e1; e += 4) {
    uint2 g[4];
#pragma unroll
    for (int j = 0; j < 4; ++j) {       // 4 independent 8B gathers in flight
      int sn = cc[j] & 0xFFFF;
      g[j] = *reinterpret_cast<const uint2*>(featbf + (size_t)sn * kIN + lane * 4);
    }
    int rr[4];
#pragma unroll
    for (int j = 0; j < 4; ++j) rr[j] = cc[j] >> 16;
#pragma unroll
    for (int j = 0; j < 4; ++j) {       // prefetch next chunk's col entries
      int ee = e + 4 + j;
      int v  = col[ee < kMsgs ? ee : kMsgs - 1];
      cc[j] = ee < e1 ? v : pad;
    }
#pragma unroll
    for (int j = 0; j < 4; ++j) {
      float4 c0 = cvr[rr[j] * 2];
      float4 c1 = cvr[rr[j] * 2 + 1];
      float4 gg;
      gg.x = __uint_as_float(g[j].x << 16);
      gg.y = __uint_as_float(g[j].x & 0xFFFF0000u);
      gg.z = __uint_as_float(g[j].y << 16);
      gg.w = __uint_as_float(g[j].y & 0xFFFF0000u);
      FMA4(acc[0], c0.x, gg) FMA4(acc[1], c0.y, gg)
      FMA4(acc[2], c0.z, gg) FMA4(acc[3], c0.w, gg)
      FMA4(acc[4], c1.x, gg) FMA4(acc[5], c1.y, gg)
      FMA4(acc[6], c1.z, gg) FMA4(acc[7], c1.w, gg)
    }
  }

  // write bf16 row, pre-swizzled so GEMM's linear global_load_lds lands swizzled
  char* rowp = (char*)aggb + (size_t)node * 4096;
  int xr = (node & 7) << 4;
#pragma unroll
  for (int b = 0; b < kNB; ++b) {
    ushort4 p;
    p.x = f2bf(acc[b].x); p.y = f2bf(acc[b].y);
    p.z = f2bf(acc[b].z); p.w = f2bf(acc[b].w);
    *reinterpret_cast<ushort4*>(rowp + ((b * 512 + lane * 8) ^ xr)) = p;
  }
}

// ---------------- path A stage 2: tiled MFMA GEMM ----------------
// out[64 x 256] per block = aggb[64][2048] @ BtT, BK=128, 16 chunks.

__global__ __launch_bounds__(512, 4)
void k_gemm(const ushort* __restrict__ aggb, const ushort* __restrict__ Bt,
            const float* __restrict__ bias, float* __restrict__ out) {
  __shared__ ushort Albs[kBM * 128];       // 16 KB  rows 256B (swizzled)
  __shared__ ushort Blds[256 * 128];       // 64 KB  rows 256B (swizzled)
  int tid  = threadIdx.x;
  int wv   = tid >> 6;          // 0..7
  int lane = tid & 63;
  int mh   = wv >> 2;           // 0..1 : rows [mh*32, +32)
  int nq   = wv & 3;            // 0..3 : cols [nq*64, +64)
  int l15  = lane & 15;
  int g4   = lane >> 4;
  int node0 = blockIdx.x * kBM;

  f32x4 acc[2][4];
#pragma unroll
  for (int mt = 0; mt < 2; ++mt)
#pragma unroll
    for (int nt = 0; nt < 4; ++nt) acc[mt][nt] = f32x4{0.f, 0.f, 0.f, 0.f};

  for (int c = 0; c < 16; ++c) {
    // stage A: 16 KB = 16 wave-issues of 1 KB (64 lanes x 16B)
#pragma unroll
    for (int i = 0; i < 2; ++i) {
      int seg = i * 8 + wv;                       // 0..15
      int lin = seg * 1024 + lane * 16;
      int row = lin >> 8;
      const char* src = (const char*)aggb + (size_t)(node0 + row) * 4096
                        + c * 256 + (lin & 255);
      gload16(src, (char*)Albs + seg * 1024);
    }
    // stage B: 64 KB = 64 wave-issues
#pragma unroll
    for (int i = 0; i < 8; ++i) {
      int seg = i * 8 + wv;                       // 0..63
      int lin = seg * 1024 + lane * 16;
      int colr = lin >> 8;
      const char* src = (const char*)Bt + (size_t)colr * 4096
                        + c * 256 + (lin & 255);
      gload16(src, (char*)Blds + seg * 1024);
    }
    asm volatile("s_waitcnt vmcnt(0)" ::: "memory");
    __syncthreads();

#pragma unroll
    for (int ks = 0; ks < 4; ++ks) {
      int kb = ks * 64 + g4 * 16;
      bf16x8 a[2], b[4];
#pragma unroll
      for (int mt = 0; mt < 2; ++mt) {
        int row = mh * 32 + mt * 16 + l15;
        a[mt] = *reinterpret_cast<const bf16x8*>(
            (const char*)Albs + row * 256 + (kb ^ ((row & 7) << 4)));
      }
#pragma unroll
      for (int nt = 0; nt < 4; ++nt) {
        int colr = nq * 64 + nt * 16 + l15;
        b[nt] = *reinterpret_cast<const bf16x8*>(
            (const char*)Blds + colr * 256 + (kb ^ ((colr & 7) << 4)));
      }
#pragma unroll
      for (int mt = 0; mt < 2; ++mt)
#pragma unroll
        for (int nt = 0; nt < 4; ++nt)
          acc[mt][nt] = __builtin_amdgcn_mfma_f32_16x16x32_bf16(a[mt], b[nt],
                                                                acc[mt][nt], 0, 0, 0);
    }
    __syncthreads();
  }

#pragma unroll
  for (int nt = 0; nt < 4; ++nt) {
    int colo = nq * 64 + nt * 16 + l15;
    float bi = bias[colo];
#pragma unroll
    for (int mt = 0; mt < 2; ++mt) {
      int rbase = node0 + mh * 32 + mt * 16 + g4 * 4;
#pragma unroll
      for (int j = 0; j < 4; ++j) {
        int row = rbase + j;
        if (row < kN) out[(size_t)row * kOUT + colo] = acc[mt][nt][j] + bi;
      }
    }
  }
}

// ---------------- path B: round-4 fused kernel (swizzled-Bt reader) ----------------

__global__ __launch_bounds__(512, 4)
void k_out_fused(const int* __restrict__ rp, const int* __restrict__ col,
                 const float* __restrict__ feat, const ushort* __restrict__ featbf,
                 const ushort* __restrict__ Bt, const float* __restrict__ comps,
                 const float* __restrict__ bias, float* __restrict__ out) {
  __shared__ ushort aggs[kTN * kKT];
  __shared__ float  cvb[kTN][17][kNB];
  int tid  = threadIdx.x;
  int wv   = tid >> 6;
  int lane = tid & 63;
  int node0 = blockIdx.x * kTN;

  for (int q = tid; q < kTN * 17; q += 512) {
    int nl = q / 17, rl = q - nl * 17;
    float val = 0.f;
    if (rl < kNRel) {
      int idx = (node0 + nl) * kNRel + rl;
      int d = rp[idx + 1] - rp[idx];
      val = d > 0 ? 1.0f / (float)d : 0.f;
    }
#pragma unroll
    for (int b = 0; b < kNB; ++b)
      cvb[nl][rl][b] = comps[rl * kNB + b] * val;
  }
  __syncthreads();

  for (int half = 0; half < 2; ++half) {
    int nl   = (wv << 1) | half;
    int node = node0 + nl;
    int e0 = rp[node * kNRel];
    int e1 = rp[node * kNRel + kNRel];

    float4 f = *reinterpret_cast<const float4*>(feat + (size_t)node * kIN + lane * 4);
    float4 acc[kNB];
#pragma unroll
    for (int b = 0; b < kNB; ++b) {
      float cs = comps[2*kR0*kNB + b];
      acc[b].x = cs * f.x; acc[b].y = cs * f.y; acc[b].z = cs * f.z; acc[b].w = cs * f.w;
    }
    const float4* cvr = reinterpret_cast<const float4*>(&cvb[nl][0][0]);
    const int pad = (16 << 16);
    int cc[4];
#pragma unroll
    for (int j = 0; j < 4; ++j) {
      int ee = e0 + j;
      int v  = col[ee < kMsgs ? ee : kMsgs - 1];
      cc[j] = ee < e1 ? v : pad;
    }
    for (int e = e0; e < e1; e += 4) {
      uint2 g[4];
#pragma unroll
      for (int j = 0; j < 4; ++j) {
        int sn = cc[j] & 0xFFFF;
        g[j] = *reinterpret_cast<const uint2*>(featbf + (size_t)sn * kIN + lane * 4);
      }
      int rr[4];
#pragma unroll
      for (int j = 0; j < 4; ++j) rr[j] = cc[j] >> 16;
#pragma unroll
      for (int j = 0; j < 4; ++j) {
        int ee = e + 4 + j;
        int v  = col[ee < kMsgs ? ee : kMsgs - 1];
        cc[j] = ee < e1 ? v : pad;
      }
#pragma unroll
      for (int j = 0; j < 4; ++j) {
        float4 c0 = cvr[rr[j] * 2];
        float4 c1 = cvr[rr[j] * 2 + 1];
        float4 gg;
        gg.x = __uint_as_float(g[j].x << 16);
        gg.y = __uint_as_float(g[j].x & 0xFFFF0000u);
        gg.z = __uint_as_float(g[j].y << 16);
        gg.w = __uint_as_float(g[j].y & 0xFFFF0000u);
        FMA4(acc[0], c0.x, gg) FMA4(acc[1], c0.y, gg)
        FMA4(acc[2], c0.z, gg) FMA4(acc[3], c0.w, gg)
        FMA4(acc[4], c1.x, gg) FMA4(acc[5], c1.y, gg)
        FMA4(acc[6], c1.z, gg) FMA4(acc[7], c1.w, gg)
      }
    }
    int xr = (nl & 7) << 4;
#pragma unroll
    for (int b = 0; b < kNB; ++b) {
      ushort4 p;
      p.x = f2bf(acc[b].x); p.y = f2bf(acc[b].y);
      p.z = f2bf(acc[b].z); p.w = f2bf(acc[b].w);
      int byteoff = nl * 4096 + ((b * 512 + lane * 8) ^ xr);
      *reinterpret_cast<ushort4*>(reinterpret_cast<char*>(aggs) + byteoff) = p;
    }
  }
  __syncthreads();

  {
    int n  = lane & 15;
    int g4 = lane >> 4;
    const char* abase = reinterpret_cast<const char*>(aggs) + n * 4096;
    int axor = (n & 7) << 4;
#pragma unroll
    for (int t = 0; t < 2; ++t) {
      int ntile = wv + t * 8;
      float bi = bias[ntile * 16 + n];
      const char* btrow = reinterpret_cast<const char*>(Bt)
                          + (size_t)(ntile * 16 + n) * 4096;
      int bxor = (n & 7) << 4;                   // (row&7) == (n&7) since ntile*16 % 8 == 0
      f32x4 acc = {0.f, 0.f, 0.f, 0.f};
#pragma unroll 4
      for (int ks = 0; ks < kKT / 32; ++ks) {
        int kb = ks * 64 + g4 * 16;
        bf16x8 af = *reinterpret_cast<const bf16x8*>(abase + (kb ^ axor));
        bf16x8 bf = *reinterpret_cast<const bf16x8*>(btrow + (kb ^ bxor));
        acc = __builtin_amdgcn_mfma_f32_16x16x32_bf16(af, bf, acc, 0, 0, 0);
      }
#pragma unroll
      for (int j = 0; j < 4; ++j) {
        int row = g4 * 4 + j;
        out[(size_t)(node0 + row) * kOUT + ntile * 16 + n] = acc[j] + bi;
      }
    }
  }
}

// ---------------- launch ----------------

extern "C" void kernel_launch(void* const* d_in, const int* in_sizes, int n_in,
                              void* d_out, int out_size, void* d_ws, size_t ws_size,
                              hipStream_t stream) {
  const int*   triples = (const int*)  d_in[0];
  const float* feat    = (const float*)d_in[1];
  const float* bases   = (const float*)d_in[2];
  const float* comps   = (const float*)d_in[3];
  const float* bias    = (const float*)d_in[4];
  float* out = (float*)d_out;

  size_t featbf_b = (size_t)kN * kIN * 2;        // 15,360,000
  size_t bt_b     = (size_t)kOUT * kKT * 2;      // 1,048,576
  size_t aggb_b   = (size_t)kMPad * kKT * 2;     // 122,945,536
  size_t csr_b    = (size_t)(kRows + kRows + 1 + kMsgs + kNScanBlk) * 4;
  bool bigws = ws_size >= featbf_b + bt_b + aggb_b + csr_b + 1024;

  char* p = (char*)d_ws;
  ushort* featbf = (ushort*)p;            p += featbf_b;
  ushort* Bt     = (ushort*)p;            p += bt_b;
  ushort* aggb   = nullptr;
  if (bigws) { aggb = (ushort*)p;         p += aggb_b; }
  int* deg    = (int*)p;
  int* rp     = deg + kRows;
  int* col    = rp + kRows + 1;
  int* blksum = col + kMsgs;

  k_fbf   <<<(kN * kIN / 4 + 255) / 256, 256, 0, stream>>>(feat, featbf);
  k_bt    <<<kKT / 16,            256, 0, stream>>>(bases, Bt);
  hipMemsetAsync(deg, 0, kRows * sizeof(int), stream);
  k_count <<<(kE + 255) / 256,    256, 0, stream>>>(triples, deg);
  k_scan1 <<<kNScanBlk,           256, 0, stream>>>(deg, rp, blksum);
  k_scan2 <<<1,                   512, 0, stream>>>(blksum);
  k_scan3 <<<(kRows + 256) / 256, 256, 0, stream>>>(rp, blksum);
  hipMemsetAsync(deg, 0, kRows * sizeof(int), stream);
  k_scatter<<<(kMsgs + 255) / 256, 256, 0, stream>>>(triples, rp, deg, col);

  if (bigws) {
    k_agg1<<<kN / 4,  256, 0, stream>>>(rp, col, feat, featbf, comps, aggb);
    k_gemm<<<kMB,     512, 0, stream>>>(aggb, Bt, bias, out);
  } else {
    k_out_fused<<<kN / kTN, 512, 0, stream>>>(rp, col, feat, featbf, Bt,
                                              comps, bias, out);
  }
}

// Round 6
// 190.688 us; speedup vs baseline: 3.2834x; 1.0068x over previous
//
#include <hip/hip_runtime.h>

// R-GCN basis-decomposed layer, fissioned:
//   k_agg1: 1 wave/node gather+combine -> aggb[30016][2048] bf16 (pre-swizzled rows)
//           (software-pipelined: gathers consumed one iteration after issue)
//   k_gemm: out = aggb @ BtT via mfma 16x16x32 bf16, BK=64 double-buffered LDS,
//           stage(next) issued before compute(cur), one vmcnt(0)+barrier per chunk
// Fallback (small ws): round-4 fused kernel (swizzled-Bt reader).
//
// ws path A (~145.6 MB): featbf | Bt | aggb | deg | rp | col | blksum
// ws path B (~22.7 MB):  featbf | Bt | deg | rp | col | blksum

namespace {
constexpr int kN     = 30000;
constexpr int kR0    = 8;
constexpr int kNRel  = 16;
constexpr int kIN    = 256;
constexpr int kOUT   = 256;
constexpr int kE     = 300000;
constexpr int kNB    = 8;
constexpr int kKT    = kNB * kIN;          // 2048
constexpr int kRows  = kN * kNRel;         // 480000
constexpr int kMsgs  = 2 * kE;             // 600000
constexpr int kScanBlk  = 1024;
constexpr int kNScanBlk = (kRows + kScanBlk - 1) / kScanBlk;   // 469
constexpr int kBM    = 64;
constexpr int kMB    = (kN + kBM - 1) / kBM;   // 469 gemm blocks
constexpr int kMPad  = kMB * kBM;              // 30016 padded rows
constexpr int kTN    = 16;                 // fused-path nodes per block
}

typedef __bf16 bf16x8 __attribute__((ext_vector_type(8)));
typedef float  f32x4  __attribute__((ext_vector_type(4)));
typedef unsigned int u32;

static __device__ __forceinline__ ushort f2bf(float x) {
  unsigned u = __float_as_uint(x);
  u += 0x7FFF + ((u >> 16) & 1);           // round-to-nearest-even
  return (ushort)(u >> 16);
}

static __device__ __forceinline__ void gload16(const void* g, void* l) {
  __builtin_amdgcn_global_load_lds(
      (const __attribute__((address_space(1))) u32*)g,
      (__attribute__((address_space(3))) u32*)l, 16, 0, 0);
}

// ---------------- prep: bf16 feature copy + degree count (merged) ----------------

__global__ void k_prep(const float* __restrict__ f, ushort* __restrict__ fb,
                       const int* __restrict__ t, int* __restrict__ deg) {
  int i = blockIdx.x * 256 + threadIdx.x;
  if (i < kN * kIN / 4) {
    float4 v = reinterpret_cast<const float4*>(f)[i];
    ushort4 p;
    p.x = f2bf(v.x); p.y = f2bf(v.y); p.z = f2bf(v.z); p.w = f2bf(v.w);
    reinterpret_cast<ushort4*>(fb)[i] = p;
  }
  if (i < kE) {
    int s = t[3*i], r = t[3*i+1], o = t[3*i+2];
    atomicAdd(&deg[s * kNRel + r], 1);
    atomicAdd(&deg[o * kNRel + kR0 + r], 1);
  }
}

// bases[2048][256] f32 -> Bt rows: col-major [256 cols][2048 k] bf16, row bytes
// XOR-swizzled by ((col&7)<<4) so GEMM LDS frag reads are spread across banks.
__global__ void k_bt(const float* __restrict__ bases, ushort* __restrict__ Bt) {
  __shared__ float tile[16][256];
  int b = blockIdx.x;            // k-block [b*16, b*16+16)
  int t = threadIdx.x;           // 256 = col
#pragma unroll
  for (int kk = 0; kk < 16; ++kk)
    tile[kk][t] = bases[(size_t)(b * 16 + kk) * kOUT + t];
  __syncthreads();
  char* dst = (char*)Bt + (size_t)t * 4096;
  int xr = (t & 7) << 4;
#pragma unroll
  for (int q = 0; q < 4; ++q) {
    ushort4 p;
    p.x = f2bf(tile[q*4+0][t]); p.y = f2bf(tile[q*4+1][t]);
    p.z = f2bf(tile[q*4+2][t]); p.w = f2bf(tile[q*4+3][t]);
    *reinterpret_cast<ushort4*>(dst + ((b * 32 + q * 8) ^ xr)) = p;
  }
}

// ---------------- CSR build ----------------

__global__ void k_scan1(const int* __restrict__ deg, int* __restrict__ rp,
                        int* __restrict__ blksum) {
  __shared__ int s[256];
  int tid = threadIdx.x;
  int base = blockIdx.x * kScanBlk + tid * 4;
  int v0 = 0, v1 = 0, v2 = 0, v3 = 0;
  if (base + 3 < kRows) {
    v0 = deg[base]; v1 = deg[base+1]; v2 = deg[base+2]; v3 = deg[base+3];
  } else {
    if (base     < kRows) v0 = deg[base];
    if (base + 1 < kRows) v1 = deg[base+1];
    if (base + 2 < kRows) v2 = deg[base+2];
  }
  int t0 = v0, t1 = t0 + v1, t2 = t1 + v2, t3 = t2 + v3;
  s[tid] = t3;
  __syncthreads();
  for (int off = 1; off < 256; off <<= 1) {
    int x = 0;
    if (tid >= off) x = s[tid - off];
    __syncthreads();
    s[tid] += x;
    __syncthreads();
  }
  int excl = tid ? s[tid-1] : 0;
  if (base     < kRows) rp[base]   = excl;
  if (base + 1 < kRows) rp[base+1] = excl + t0;
  if (base + 2 < kRows) rp[base+2] = excl + t1;
  if (base + 3 < kRows) rp[base+3] = excl + t2;
  if (tid == 255) blksum[blockIdx.x] = s[255];
}

__global__ void k_scan2(int* __restrict__ blksum) {
  __shared__ int s[512];
  int tid = threadIdx.x;
  s[tid] = (tid < kNScanBlk) ? blksum[tid] : 0;
  __syncthreads();
  for (int off = 1; off < 512; off <<= 1) {
    int x = 0;
    if (tid >= off) x = s[tid - off];
    __syncthreads();
    s[tid] += x;
    __syncthreads();
  }
  if (tid < kNScanBlk) blksum[tid] = tid ? s[tid-1] : 0;
}

__global__ void k_scan3(int* __restrict__ rp, const int* __restrict__ blksum) {
  int i = blockIdx.x * 256 + threadIdx.x;
  if (i < kRows)       rp[i] += blksum[i >> 10];
  else if (i == kRows) rp[i]  = kMsgs;
}

// cursor = atomicSub on the still-live deg counts (no second memset needed)
__global__ void k_scatter(const int* __restrict__ t, const int* __restrict__ rp,
                          int* __restrict__ deg, int* __restrict__ col) {
  int m = blockIdx.x * 256 + threadIdx.x;
  if (m >= kMsgs) return;
  int e = (m < kE) ? m : m - kE;
  int s = t[3*e], r = t[3*e+1], o = t[3*e+2];
  int rr, tn, sn;
  if (m < kE) { rr = r;        tn = s; sn = o; }
  else        { rr = kR0 + r;  tn = o; sn = s; }
  int idx = tn * kNRel + rr;
  int pos = rp[idx] + (atomicSub(&deg[idx], 1) - 1);
  col[pos] = (rr << 16) | sn;
}

#define FMA4(A, S, G) \
  A.x += (S) * G.x; A.y += (S) * G.y; A.z += (S) * G.z; A.w += (S) * G.w;

// ---------------- path A stage 1: one wave per node, software-pipelined ----------------

__global__ __launch_bounds__(256, 4)
void k_agg1(const int* __restrict__ rp, const int* __restrict__ col,
            const float* __restrict__ feat, const ushort* __restrict__ featbf,
            const float* __restrict__ comps, ushort* __restrict__ aggb) {
  __shared__ float cvb[4][17][kNB];     // per-wave coeff table, row 16 = zeros
  int wv   = threadIdx.x >> 6;
  int lane = threadIdx.x & 63;
  int node = blockIdx.x * 4 + wv;       // kN % 4 == 0

  if (lane < 17) {
    float val = 0.f;
    if (lane < kNRel) {
      int idx = node * kNRel + lane;
      int d = rp[idx + 1] - rp[idx];
      val = d > 0 ? 1.0f / (float)d : 0.f;
    }
#pragma unroll
    for (int b = 0; b < kNB; ++b)
      cvb[wv][lane][b] = comps[lane * kNB + b] * val;
  }
  __syncthreads();

  int e0 = rp[node * kNRel];
  int e1 = rp[node * kNRel + kNRel];

  float4 f = *reinterpret_cast<const float4*>(feat + (size_t)node * kIN + lane * 4);
  float4 acc[kNB];
#pragma unroll
  for (int b = 0; b < kNB; ++b) {       // self-loop (relation 16, val = 1)
    float cs = comps[2*kR0*kNB + b];
    acc[b].x = cs * f.x; acc[b].y = cs * f.y; acc[b].z = cs * f.z; acc[b].w = cs * f.w;
  }

  const float4* cvr = reinterpret_cast<const float4*>(&cvb[wv][0][0]);
  const int pad = (16 << 16);           // rel slot 16 -> zero coeffs (reads row 0)

  // prologue: cc0 = chunk e0, g0 = gathers(cc0), cc1 = chunk e0+4
  int cc0[4], cc1[4];
  uint2 g0[4];
#pragma unroll
  for (int j = 0; j < 4; ++j) {
    int ee = e0 + j;
    int v  = col[ee < kMsgs ? ee : kMsgs - 1];
    cc0[j] = ee < e1 ? v : pad;
  }
#pragma unroll
  for (int j = 0; j < 4; ++j)
    g0[j] = *reinterpret_cast<const uint2*>(featbf + (size_t)(cc0[j] & 0xFFFF) * kIN + lane * 4);
#pragma unroll
  for (int j = 0; j < 4; ++j) {
    int ee = e0 + 4 + j;
    int v  = col[ee < kMsgs ? ee : kMsgs - 1];
    cc1[j] = ee < e1 ? v : pad;
  }

#pragma unroll 2
  for (int e = e0; e < e1; e += 4) {
    uint2 g1[4];
#pragma unroll
    for (int j = 0; j < 4; ++j)         // issue next chunk's gathers (cc1 ready)
      g1[j] = *reinterpret_cast<const uint2*>(featbf + (size_t)(cc1[j] & 0xFFFF) * kIN + lane * 4);
    int cc2[4];
#pragma unroll
    for (int j = 0; j < 4; ++j) {       // prefetch col two chunks ahead
      int ee = e + 8 + j;
      int v  = col[ee < kMsgs ? ee : kMsgs - 1];
      cc2[j] = ee < e1 ? v : pad;
    }
#pragma unroll
    for (int j = 0; j < 4; ++j) {       // compute with the PREVIOUS chunk's gathers
      int r = cc0[j] >> 16;
      float4 c0 = cvr[r * 2];
      float4 c1 = cvr[r * 2 + 1];
      float4 gg;
      gg.x = __uint_as_float(g0[j].x << 16);
      gg.y = __uint_as_float(g0[j].x & 0xFFFF0000u);
      gg.z = __uint_as_float(g0[j].y << 16);
      gg.w = __uint_as_float(g0[j].y & 0xFFFF0000u);
      FMA4(acc[0], c0.x, gg) FMA4(acc[1], c0.y, gg)
      FMA4(acc[2], c0.z, gg) FMA4(acc[3], c0.w, gg)
      FMA4(acc[4], c1.x, gg) FMA4(acc[5], c1.y, gg)
      FMA4(acc[6], c1.z, gg) FMA4(acc[7], c1.w, gg)
    }
#pragma unroll
    for (int j = 0; j < 4; ++j) {       // shift pipeline
      cc0[j] = cc1[j]; cc1[j] = cc2[j]; g0[j] = g1[j];
    }
  }

  // write bf16 row, pre-swizzled so GEMM's linear global_load_lds lands swizzled
  char* rowp = (char*)aggb + (size_t)node * 4096;
  int xr = (node & 7) << 4;
#pragma unroll
  for (int b = 0; b < kNB; ++b) {
    ushort4 p;
    p.x = f2bf(acc[b].x); p.y = f2bf(acc[b].y);
    p.z = f2bf(acc[b].z); p.w = f2bf(acc[b].w);
    *reinterpret_cast<ushort4*>(rowp + ((b * 512 + lane * 8) ^ xr)) = p;
  }
}

// ---------------- path A stage 2: tiled MFMA GEMM, BK=64, double-buffered ----------------
// out[64 x 256] per block = aggb[64][2048] @ BtT, 32 chunks of BK=64.

__global__ __launch_bounds__(512, 4)
void k_gemm(const ushort* __restrict__ aggb, const ushort* __restrict__ Bt,
            const float* __restrict__ bias, float* __restrict__ out) {
  __shared__ ushort Albs[2][kBM * 64];     // 2 x  8 KB, row stride 128 B (swizzled)
  __shared__ ushort Blds[2][256 * 64];     // 2 x 32 KB, row stride 128 B (swizzled)
  int tid  = threadIdx.x;
  int wv   = tid >> 6;          // 0..7
  int lane = tid & 63;
  int mh   = wv >> 2;           // 0..1 : rows [mh*32, +32)
  int nq   = wv & 3;            // 0..3 : cols [nq*64, +64)
  int l15  = lane & 15;
  int g4   = lane >> 4;
  int node0 = blockIdx.x * kBM;

  f32x4 acc[2][4];
#pragma unroll
  for (int mt = 0; mt < 2; ++mt)
#pragma unroll
    for (int nt = 0; nt < 4; ++nt) acc[mt][nt] = f32x4{0.f, 0.f, 0.f, 0.f};

  // stage chunk c (128 B per row) into buffer buf
  auto stage = [&](int c, int buf) {
    {   // A: 8 KB = 8 segs of 1 KB, one per wave
      int lin = wv * 1024 + lane * 16;
      int row = lin >> 7;
      const char* src = (const char*)aggb + (size_t)(node0 + row) * 4096
                        + c * 128 + (lin & 127);
      gload16(src, (char*)Albs[buf] + wv * 1024);
    }
#pragma unroll
    for (int i = 0; i < 4; ++i) {   // B: 32 KB = 32 segs, 4 per wave
      int seg = wv * 4 + i;
      int lin = seg * 1024 + lane * 16;
      int colr = lin >> 7;
      const char* src = (const char*)Bt + (size_t)colr * 4096
                        + c * 128 + (lin & 127);
      gload16(src, (char*)Blds[buf] + seg * 1024);
    }
  };

  stage(0, 0);
  asm volatile("s_waitcnt vmcnt(0)" ::: "memory");
  __syncthreads();

  int cur = 0;
  for (int c = 0; c < 32; ++c) {
    if (c + 1 < 32) stage(c + 1, cur ^ 1);       // prefetch next chunk
#pragma unroll
    for (int ks = 0; ks < 2; ++ks) {
      int kb = ks * 64 + g4 * 16;
      bf16x8 a[2], b[4];
#pragma unroll
      for (int mt = 0; mt < 2; ++mt) {
        int row = mh * 32 + mt * 16 + l15;
        a[mt] = *reinterpret_cast<const bf16x8*>(
            (const char*)Albs[cur] + row * 128 + (kb ^ ((row & 7) << 4)));
      }
#pragma unroll
      for (int nt = 0; nt < 4; ++nt) {
        int colr = nq * 64 + nt * 16 + l15;
        b[nt] = *reinterpret_cast<const bf16x8*>(
            (const char*)Blds[cur] + colr * 128 + (kb ^ ((colr & 7) << 4)));
      }
#pragma unroll
      for (int mt = 0; mt < 2; ++mt)
#pragma unroll
        for (int nt = 0; nt < 4; ++nt)
          acc[mt][nt] = __builtin_amdgcn_mfma_f32_16x16x32_bf16(a[mt], b[nt],
                                                                acc[mt][nt], 0, 0, 0);
    }
    asm volatile("s_waitcnt vmcnt(0)" ::: "memory");  // next-chunk stage landed
    __syncthreads();                                   // all waves done with cur
    cur ^= 1;
  }

#pragma unroll
  for (int nt = 0; nt < 4; ++nt) {
    int colo = nq * 64 + nt * 16 + l15;
    float bi = bias[colo];
#pragma unroll
    for (int mt = 0; mt < 2; ++mt) {
      int rbase = node0 + mh * 32 + mt * 16 + g4 * 4;
#pragma unroll
      for (int j = 0; j < 4; ++j) {
        int row = rbase + j;
        if (row < kN) out[(size_t)row * kOUT + colo] = acc[mt][nt][j] + bi;
      }
    }
  }
}

// ---------------- path B: fused fallback (swizzled-Bt reader) ----------------

__global__ __launch_bounds__(512, 4)
void k_out_fused(const int* __restrict__ rp, const int* __restrict__ col,
                 const float* __restrict__ feat, const ushort* __restrict__ featbf,
                 const ushort* __restrict__ Bt, const float* __restrict__ comps,
                 const float* __restrict__ bias, float* __restrict__ out) {
  __shared__ ushort aggs[kTN * kKT];
  __shared__ float  cvb[kTN][17][kNB];
  int tid  = threadIdx.x;
  int wv   = tid >> 6;
  int lane = tid & 63;
  int node0 = blockIdx.x * kTN;

  for (int q = tid; q < kTN * 17; q += 512) {
    int nl = q / 17, rl = q - nl * 17;
    float val = 0.f;
    if (rl < kNRel) {
      int idx = (node0 + nl) * kNRel + rl;
      int d = rp[idx + 1] - rp[idx];
      val = d > 0 ? 1.0f / (float)d : 0.f;
    }
#pragma unroll
    for (int b = 0; b < kNB; ++b)
      cvb[nl][rl][b] = comps[rl * kNB + b] * val;
  }
  __syncthreads();

  for (int half = 0; half < 2; ++half) {
    int nl   = (wv << 1) | half;
    int node = node0 + nl;
    int e0 = rp[node * kNRel];
    int e1 = rp[node * kNRel + kNRel];

    float4 f = *reinterpret_cast<const float4*>(feat + (size_t)node * kIN + lane * 4);
    float4 acc[kNB];
#pragma unroll
    for (int b = 0; b < kNB; ++b) {
      float cs = comps[2*kR0*kNB + b];
      acc[b].x = cs * f.x; acc[b].y = cs * f.y; acc[b].z = cs * f.z; acc[b].w = cs * f.w;
    }
    const float4* cvr = reinterpret_cast<const float4*>(&cvb[nl][0][0]);
    const int pad = (16 << 16);
    int cc[4];
#pragma unroll
    for (int j = 0; j < 4; ++j) {
      int ee = e0 + j;
      int v  = col[ee < kMsgs ? ee : kMsgs - 1];
      cc[j] = ee < e1 ? v : pad;
    }
    for (int e = e0; e < e1; e += 4) {
      uint2 g[4];
#pragma unroll
      for (int j = 0; j < 4; ++j) {
        int sn = cc[j] & 0xFFFF;
        g[j] = *reinterpret_cast<const uint2*>(featbf + (size_t)sn * kIN + lane * 4);
      }
      int rr[4];
#pragma unroll
      for (int j = 0; j < 4; ++j) rr[j] = cc[j] >> 16;
#pragma unroll
      for (int j = 0; j < 4; ++j) {
        int ee = e + 4 + j;
        int v  = col[ee < kMsgs ? ee : kMsgs - 1];
        cc[j] = ee < e1 ? v : pad;
      }
#pragma unroll
      for (int j = 0; j < 4; ++j) {
        float4 c0 = cvr[rr[j] * 2];
        float4 c1 = cvr[rr[j] * 2 + 1];
        float4 gg;
        gg.x = __uint_as_float(g[j].x << 16);
        gg.y = __uint_as_float(g[j].x & 0xFFFF0000u);
        gg.z = __uint_as_float(g[j].y << 16);
        gg.w = __uint_as_float(g[j].y & 0xFFFF0000u);
        FMA4(acc[0], c0.x, gg) FMA4(acc[1], c0.y, gg)
        FMA4(acc[2], c0.z, gg) FMA4(acc[3], c0.w, gg)
        FMA4(acc[4], c1.x, gg) FMA4(acc[5], c1.y, gg)
        FMA4(acc[6], c1.z, gg) FMA4(acc[7], c1.w, gg)
      }
    }
    int xr = (nl & 7) << 4;
#pragma unroll
    for (int b = 0; b < kNB; ++b) {
      ushort4 p;
      p.x = f2bf(acc[b].x); p.y = f2bf(acc[b].y);
      p.z = f2bf(acc[b].z); p.w = f2bf(acc[b].w);
      int byteoff = nl * 4096 + ((b * 512 + lane * 8) ^ xr);
      *reinterpret_cast<ushort4*>(reinterpret_cast<char*>(aggs) + byteoff) = p;
    }
  }
  __syncthreads();

  {
    int n  = lane & 15;
    int g4 = lane >> 4;
    const char* abase = reinterpret_cast<const char*>(aggs) + n * 4096;
    int axor = (n & 7) << 4;
#pragma unroll
    for (int t = 0; t < 2; ++t) {
      int ntile = wv + t * 8;
      float bi = bias[ntile * 16 + n];
      const char* btrow = reinterpret_cast<const char*>(Bt)
                          + (size_t)(ntile * 16 + n) * 4096;
      int bxor = (n & 7) << 4;
      f32x4 acc = {0.f, 0.f, 0.f, 0.f};
#pragma unroll 4
      for (int ks = 0; ks < kKT / 32; ++ks) {
        int kb = ks * 64 + g4 * 16;
        bf16x8 af = *reinterpret_cast<const bf16x8*>(abase + (kb ^ axor));
        bf16x8 bf = *reinterpret_cast<const bf16x8*>(btrow + (kb ^ bxor));
        acc = __builtin_amdgcn_mfma_f32_16x16x32_bf16(af, bf, acc, 0, 0, 0);
      }
#pragma unroll
      for (int j = 0; j < 4; ++j) {
        int row = g4 * 4 + j;
        out[(size_t)(node0 + row) * kOUT + ntile * 16 + n] = acc[j] + bi;
      }
    }
  }
}

// ---------------- launch ----------------

extern "C" void kernel_launch(void* const* d_in, const int* in_sizes, int n_in,
                              void* d_out, int out_size, void* d_ws, size_t ws_size,
                              hipStream_t stream) {
  const int*   triples = (const int*)  d_in[0];
  const float* feat    = (const float*)d_in[1];
  const float* bases   = (const float*)d_in[2];
  const float* comps   = (const float*)d_in[3];
  const float* bias    = (const float*)d_in[4];
  float* out = (float*)d_out;

  size_t featbf_b = (size_t)kN * kIN * 2;        // 15,360,000
  size_t bt_b     = (size_t)kOUT * kKT * 2;      // 1,048,576
  size_t aggb_b   = (size_t)kMPad * kKT * 2;     // 122,945,536
  size_t csr_b    = (size_t)(kRows + kRows + 1 + kMsgs + kNScanBlk) * 4;
  bool bigws = ws_size >= featbf_b + bt_b + aggb_b + csr_b + 1024;

  char* p = (char*)d_ws;
  ushort* featbf = (ushort*)p;            p += featbf_b;
  ushort* Bt     = (ushort*)p;            p += bt_b;
  ushort* aggb   = nullptr;
  if (bigws) { aggb = (ushort*)p;         p += aggb_b; }
  int* deg    = (int*)p;
  int* rp     = deg + kRows;
  int* col    = rp + kRows + 1;
  int* blksum = col + kMsgs;

  hipMemsetAsync(deg, 0, kRows * sizeof(int), stream);
  k_prep  <<<(kN * kIN / 4 + 255) / 256, 256, 0, stream>>>(feat, featbf, triples, deg);
  k_bt    <<<kKT / 16,            256, 0, stream>>>(bases, Bt);
  k_scan1 <<<kNScanBlk,           256, 0, stream>>>(deg, rp, blksum);
  k_scan2 <<<1,                   512, 0, stream>>>(blksum);
  k_scan3 <<<(kRows + 256) / 256, 256, 0, stream>>>(rp, blksum);
  k_scatter<<<(kMsgs + 255) / 256, 256, 0, stream>>>(triples, rp, deg, col);

  if (bigws) {
    k_agg1<<<kN / 4,  256, 0, stream>>>(rp, col, feat, featbf, comps, aggb);
    k_gemm<<<kMB,     512, 0, stream>>>(aggb, Bt, bias, out);
  } else {
    k_out_fused<<<kN / kTN, 512, 0, stream>>>(rp, col, feat, featbf, Bt,
                                              comps, bias, out);
  }
}

// Round 7
// 182.710 us; speedup vs baseline: 3.4268x; 1.0437x over previous
//
#include <hip/hip_runtime.h>

// R-GCN basis-decomposed layer, fissioned:
//   k_agg1: 1 wave/node gather+combine -> aggb[30016][2048] bf16 (pre-swizzled rows)
//           scalar-path col reads (SGPR), v_pk_fma_f32 combine, bf16 self-feature
//   k_gemm: out = aggb @ BtT via mfma 16x16x32 bf16, BK=64 double-buffered LDS
// Fallback (small ws): fused kernel (swizzled-Bt reader).
//
// ws path A (~145.6 MB): featbf | Bt | aggb | deg | rp | col | blksum
// ws path B (~22.7 MB):  featbf | Bt | deg | rp | col | blksum

namespace {
constexpr int kN     = 30000;
constexpr int kR0    = 8;
constexpr int kNRel  = 16;
constexpr int kIN    = 256;
constexpr int kOUT   = 256;
constexpr int kE     = 300000;
constexpr int kNB    = 8;
constexpr int kKT    = kNB * kIN;          // 2048
constexpr int kRows  = kN * kNRel;         // 480000
constexpr int kMsgs  = 2 * kE;             // 600000
constexpr int kScanBlk  = 1024;
constexpr int kNScanBlk = (kRows + kScanBlk - 1) / kScanBlk;   // 469
constexpr int kBM    = 64;
constexpr int kMB    = (kN + kBM - 1) / kBM;   // 469 gemm blocks
constexpr int kMPad  = kMB * kBM;              // 30016 padded rows
constexpr int kTN    = 16;                 // fused-path nodes per block
}

typedef __bf16 bf16x8 __attribute__((ext_vector_type(8)));
typedef float  f32x4  __attribute__((ext_vector_type(4)));
typedef float  f32x2  __attribute__((ext_vector_type(2)));
typedef float  f32x4v __attribute__((ext_vector_type(4)));
typedef unsigned int u32;

static __device__ __forceinline__ ushort f2bf(float x) {
  unsigned u = __float_as_uint(x);
  u += 0x7FFF + ((u >> 16) & 1);           // round-to-nearest-even
  return (ushort)(u >> 16);
}

static __device__ __forceinline__ void gload16(const void* g, void* l) {
  __builtin_amdgcn_global_load_lds(
      (const __attribute__((address_space(1))) u32*)g,
      (__attribute__((address_space(3))) u32*)l, 16, 0, 0);
}

// acc.lo += C.lo*G.lo ; acc.hi += C.lo*G.hi   (broadcast C low half)
#define PKFMA_LO(ACC, G, C) \
  asm("v_pk_fma_f32 %0, %1, %2, %0 op_sel_hi:[1,0,1]" : "+v"(ACC) : "v"(G), "v"(C))
// acc.lo += C.hi*G.lo ; acc.hi += C.hi*G.hi   (broadcast C high half)
#define PKFMA_HI(ACC, G, C) \
  asm("v_pk_fma_f32 %0, %1, %2, %0 op_sel:[0,1,0] op_sel_hi:[1,1,1]" : "+v"(ACC) : "v"(G), "v"(C))

// ---------------- prep: bf16 feature copy + degree count (merged) ----------------

__global__ void k_prep(const float* __restrict__ f, ushort* __restrict__ fb,
                       const int* __restrict__ t, int* __restrict__ deg) {
  int i = blockIdx.x * 256 + threadIdx.x;
  if (i < kN * kIN / 4) {
    float4 v = reinterpret_cast<const float4*>(f)[i];
    ushort4 p;
    p.x = f2bf(v.x); p.y = f2bf(v.y); p.z = f2bf(v.z); p.w = f2bf(v.w);
    reinterpret_cast<ushort4*>(fb)[i] = p;
  }
  if (i < kE) {
    int s = t[3*i], r = t[3*i+1], o = t[3*i+2];
    atomicAdd(&deg[s * kNRel + r], 1);
    atomicAdd(&deg[o * kNRel + kR0 + r], 1);
  }
}

// bases[2048][256] f32 -> Bt rows: col-major [256 cols][2048 k] bf16, row bytes
// XOR-swizzled by ((col&7)<<4) so GEMM LDS frag reads are spread across banks.
__global__ void k_bt(const float* __restrict__ bases, ushort* __restrict__ Bt) {
  __shared__ float tile[16][256];
  int b = blockIdx.x;            // k-block [b*16, b*16+16)
  int t = threadIdx.x;           // 256 = col
#pragma unroll
  for (int kk = 0; kk < 16; ++kk)
    tile[kk][t] = bases[(size_t)(b * 16 + kk) * kOUT + t];
  __syncthreads();
  char* dst = (char*)Bt + (size_t)t * 4096;
  int xr = (t & 7) << 4;
#pragma unroll
  for (int q = 0; q < 4; ++q) {
    ushort4 p;
    p.x = f2bf(tile[q*4+0][t]); p.y = f2bf(tile[q*4+1][t]);
    p.z = f2bf(tile[q*4+2][t]); p.w = f2bf(tile[q*4+3][t]);
    *reinterpret_cast<ushort4*>(dst + ((b * 32 + q * 8) ^ xr)) = p;
  }
}

// ---------------- CSR build ----------------

__global__ void k_scan1(const int* __restrict__ deg, int* __restrict__ rp,
                        int* __restrict__ blksum) {
  __shared__ int s[256];
  int tid = threadIdx.x;
  int base = blockIdx.x * kScanBlk + tid * 4;
  int v0 = 0, v1 = 0, v2 = 0, v3 = 0;
  if (base + 3 < kRows) {
    v0 = deg[base]; v1 = deg[base+1]; v2 = deg[base+2]; v3 = deg[base+3];
  } else {
    if (base     < kRows) v0 = deg[base];
    if (base + 1 < kRows) v1 = deg[base+1];
    if (base + 2 < kRows) v2 = deg[base+2];
  }
  int t0 = v0, t1 = t0 + v1, t2 = t1 + v2, t3 = t2 + v3;
  s[tid] = t3;
  __syncthreads();
  for (int off = 1; off < 256; off <<= 1) {
    int x = 0;
    if (tid >= off) x = s[tid - off];
    __syncthreads();
    s[tid] += x;
    __syncthreads();
  }
  int excl = tid ? s[tid-1] : 0;
  if (base     < kRows) rp[base]   = excl;
  if (base + 1 < kRows) rp[base+1] = excl + t0;
  if (base + 2 < kRows) rp[base+2] = excl + t1;
  if (base + 3 < kRows) rp[base+3] = excl + t2;
  if (tid == 255) blksum[blockIdx.x] = s[255];
}

__global__ void k_scan2(int* __restrict__ blksum) {
  __shared__ int s[512];
  int tid = threadIdx.x;
  s[tid] = (tid < kNScanBlk) ? blksum[tid] : 0;
  __syncthreads();
  for (int off = 1; off < 512; off <<= 1) {
    int x = 0;
    if (tid >= off) x = s[tid - off];
    __syncthreads();
    s[tid] += x;
    __syncthreads();
  }
  if (tid < kNScanBlk) blksum[tid] = tid ? s[tid-1] : 0;
}

__global__ void k_scan3(int* __restrict__ rp, const int* __restrict__ blksum) {
  int i = blockIdx.x * 256 + threadIdx.x;
  if (i < kRows)       rp[i] += blksum[i >> 10];
  else if (i == kRows) rp[i]  = kMsgs;
}

// cursor = atomicSub on the still-live deg counts (no second memset needed)
__global__ void k_scatter(const int* __restrict__ t, const int* __restrict__ rp,
                          int* __restrict__ deg, int* __restrict__ col) {
  int m = blockIdx.x * 256 + threadIdx.x;
  if (m >= kMsgs) return;
  int e = (m < kE) ? m : m - kE;
  int s = t[3*e], r = t[3*e+1], o = t[3*e+2];
  int rr, tn, sn;
  if (m < kE) { rr = r;        tn = s; sn = o; }
  else        { rr = kR0 + r;  tn = o; sn = s; }
  int idx = tn * kNRel + rr;
  int pos = rp[idx] + (atomicSub(&deg[idx], 1) - 1);
  col[pos] = (rr << 16) | sn;
}

#define FMA4(A, S, G) \
  A.x += (S) * G.x; A.y += (S) * G.y; A.z += (S) * G.z; A.w += (S) * G.w;

// ---------------- path A stage 1: one wave per node, scalar col path ----------------

__global__ __launch_bounds__(256, 6)
void k_agg1(const int* __restrict__ rp, const int* __restrict__ col,
            const ushort* __restrict__ featbf, const float* __restrict__ comps,
            ushort* __restrict__ aggb) {
  __shared__ float cvb[4][17][kNB];     // per-wave coeff table, row 16 = zeros
  int wv   = threadIdx.x >> 6;
  int lane = threadIdx.x & 63;
  int node = blockIdx.x * 4 + wv;       // kN % 4 == 0

  if (lane < 17) {
    float val = 0.f;
    if (lane < kNRel) {
      int idx = node * kNRel + lane;
      int d = rp[idx + 1] - rp[idx];
      val = d > 0 ? 1.0f / (float)d : 0.f;
    }
#pragma unroll
    for (int b = 0; b < kNB; ++b)
      cvb[wv][lane][b] = comps[lane * kNB + b] * val;
  }
  __syncthreads();

  int se0 = __builtin_amdgcn_readfirstlane(rp[node * kNRel]);
  int se1 = __builtin_amdgcn_readfirstlane(rp[node * kNRel + kNRel]);

  // self-loop init (relation 16, val = 1) from bf16 features
  f32x2 accp[2 * kNB];                  // accp[2b]=ch01, accp[2b+1]=ch23 of basis b
  {
    uint2 sf = *reinterpret_cast<const uint2*>(featbf + (size_t)node * kIN + lane * 4);
    f32x2 p01, p23;
    p01.x = __uint_as_float(sf.x << 16);
    p01.y = __uint_as_float(sf.x & 0xFFFF0000u);
    p23.x = __uint_as_float(sf.y << 16);
    p23.y = __uint_as_float(sf.y & 0xFFFF0000u);
#pragma unroll
    for (int b = 0; b < kNB; ++b) {
      float cs = comps[2*kR0*kNB + b];
      accp[2*b]     = p01 * cs;
      accp[2*b + 1] = p23 * cs;
    }
  }

  const int pad = (16 << 16);           // rel slot 16 -> zero coeffs, node 0 row
  int voff = lane * 4;                  // element offset within a feature row

  // prologue: scalar col values for first chunk
  int sc[4];
#pragma unroll
  for (int j = 0; j < 4; ++j) {
    int ee = se0 + j;
    int ic = ee < se1 ? ee : 0;
    int v  = col[ic];
    sc[j] = ee < se1 ? v : pad;
  }

  for (int e = se0; e < se1; e += 4) {
    // issue 4 gathers: scalar row base + loop-invariant lane offset
    uint2 g[4];
#pragma unroll
    for (int j = 0; j < 4; ++j) {
      const ushort* rowp = featbf + (size_t)(sc[j] & 0xFFFF) * kIN;
      g[j] = *reinterpret_cast<const uint2*>(rowp + voff);
    }
    int sr[4];
#pragma unroll
    for (int j = 0; j < 4; ++j) sr[j] = sc[j] >> 16;
    // prefetch next chunk's col values (scalar loads, consumed next iter)
#pragma unroll
    for (int j = 0; j < 4; ++j) {
      int ee = e + 4 + j;
      int ic = ee < se1 ? ee : 0;
      int v  = col[ic];
      sc[j] = ee < se1 ? v : pad;
    }
    // combine: 16 v_pk_fma_f32 per message, coeff broadcast via op_sel
#pragma unroll
    for (int j = 0; j < 4; ++j) {
      f32x4v cA = *reinterpret_cast<const f32x4v*>(&cvb[wv][sr[j]][0]);
      f32x4v cB = *reinterpret_cast<const f32x4v*>(&cvb[wv][sr[j]][4]);
      f32x2 p01, p23;
      p01.x = __uint_as_float(g[j].x << 16);
      p01.y = __uint_as_float(g[j].x & 0xFFFF0000u);
      p23.x = __uint_as_float(g[j].y << 16);
      p23.y = __uint_as_float(g[j].y & 0xFFFF0000u);
      f32x2 cAl = cA.lo, cAh = cA.hi, cBl = cB.lo, cBh = cB.hi;
      PKFMA_LO(accp[0],  p01, cAl); PKFMA_LO(accp[1],  p23, cAl);   // b0
      PKFMA_HI(accp[2],  p01, cAl); PKFMA_HI(accp[3],  p23, cAl);   // b1
      PKFMA_LO(accp[4],  p01, cAh); PKFMA_LO(accp[5],  p23, cAh);   // b2
      PKFMA_HI(accp[6],  p01, cAh); PKFMA_HI(accp[7],  p23, cAh);   // b3
      PKFMA_LO(accp[8],  p01, cBl); PKFMA_LO(accp[9],  p23, cBl);   // b4
      PKFMA_HI(accp[10], p01, cBl); PKFMA_HI(accp[11], p23, cBl);   // b5
      PKFMA_LO(accp[12], p01, cBh); PKFMA_LO(accp[13], p23, cBh);   // b6
      PKFMA_HI(accp[14], p01, cBh); PKFMA_HI(accp[15], p23, cBh);   // b7
    }
  }

  // write bf16 row, pre-swizzled so GEMM's linear global_load_lds lands swizzled
  char* rowp = (char*)aggb + (size_t)node * 4096;
  int xr = (node & 7) << 4;
#pragma unroll
  for (int b = 0; b < kNB; ++b) {
    ushort4 p;
    p.x = f2bf(accp[2*b].x);     p.y = f2bf(accp[2*b].y);
    p.z = f2bf(accp[2*b + 1].x); p.w = f2bf(accp[2*b + 1].y);
    *reinterpret_cast<ushort4*>(rowp + ((b * 512 + lane * 8) ^ xr)) = p;
  }
}

// ---------------- path A stage 2: tiled MFMA GEMM, BK=64, double-buffered ----------------

__global__ __launch_bounds__(512, 4)
void k_gemm(const ushort* __restrict__ aggb, const ushort* __restrict__ Bt,
            const float* __restrict__ bias, float* __restrict__ out) {
  __shared__ ushort Albs[2][kBM * 64];     // 2 x  8 KB, row stride 128 B (swizzled)
  __shared__ ushort Blds[2][256 * 64];     // 2 x 32 KB, row stride 128 B (swizzled)
  int tid  = threadIdx.x;
  int wv   = tid >> 6;          // 0..7
  int lane = tid & 63;
  int mh   = wv >> 2;           // 0..1 : rows [mh*32, +32)
  int nq   = wv & 3;            // 0..3 : cols [nq*64, +64)
  int l15  = lane & 15;
  int g4   = lane >> 4;
  int node0 = blockIdx.x * kBM;

  f32x4 acc[2][4];
#pragma unroll
  for (int mt = 0; mt < 2; ++mt)
#pragma unroll
    for (int nt = 0; nt < 4; ++nt) acc[mt][nt] = f32x4{0.f, 0.f, 0.f, 0.f};

  auto stage = [&](int c, int buf) {
    {   // A: 8 KB = 8 segs of 1 KB, one per wave
      int lin = wv * 1024 + lane * 16;
      int row = lin >> 7;
      const char* src = (const char*)aggb + (size_t)(node0 + row) * 4096
                        + c * 128 + (lin & 127);
      gload16(src, (char*)Albs[buf] + wv * 1024);
    }
#pragma unroll
    for (int i = 0; i < 4; ++i) {   // B: 32 KB = 32 segs, 4 per wave
      int seg = wv * 4 + i;
      int lin = seg * 1024 + lane * 16;
      int colr = lin >> 7;
      const char* src = (const char*)Bt + (size_t)colr * 4096
                        + c * 128 + (lin & 127);
      gload16(src, (char*)Blds[buf] + seg * 1024);
    }
  };

  stage(0, 0);
  asm volatile("s_waitcnt vmcnt(0)" ::: "memory");
  __syncthreads();

  int cur = 0;
  for (int c = 0; c < 32; ++c) {
    if (c + 1 < 32) stage(c + 1, cur ^ 1);       // prefetch next chunk
#pragma unroll
    for (int ks = 0; ks < 2; ++ks) {
      int kb = ks * 64 + g4 * 16;
      bf16x8 a[2], b[4];
#pragma unroll
      for (int mt = 0; mt < 2; ++mt) {
        int row = mh * 32 + mt * 16 + l15;
        a[mt] = *reinterpret_cast<const bf16x8*>(
            (const char*)Albs[cur] + row * 128 + (kb ^ ((row & 7) << 4)));
      }
#pragma unroll
      for (int nt = 0; nt < 4; ++nt) {
        int colr = nq * 64 + nt * 16 + l15;
        b[nt] = *reinterpret_cast<const bf16x8*>(
            (const char*)Blds[cur] + colr * 128 + (kb ^ ((colr & 7) << 4)));
      }
#pragma unroll
      for (int mt = 0; mt < 2; ++mt)
#pragma unroll
        for (int nt = 0; nt < 4; ++nt)
          acc[mt][nt] = __builtin_amdgcn_mfma_f32_16x16x32_bf16(a[mt], b[nt],
                                                                acc[mt][nt], 0, 0, 0);
    }
    asm volatile("s_waitcnt vmcnt(0)" ::: "memory");  // next-chunk stage landed
    __syncthreads();                                   // all waves done with cur
    cur ^= 1;
  }

#pragma unroll
  for (int nt = 0; nt < 4; ++nt) {
    int colo = nq * 64 + nt * 16 + l15;
    float bi = bias[colo];
#pragma unroll
    for (int mt = 0; mt < 2; ++mt) {
      int rbase = node0 + mh * 32 + mt * 16 + g4 * 4;
#pragma unroll
      for (int j = 0; j < 4; ++j) {
        int row = rbase + j;
        if (row < kN) out[(size_t)row * kOUT + colo] = acc[mt][nt][j] + bi;
      }
    }
  }
}

// ---------------- path B: fused fallback (swizzled-Bt reader) ----------------

__global__ __launch_bounds__(512, 4)
void k_out_fused(const int* __restrict__ rp, const int* __restrict__ col,
                 const float* __restrict__ feat, const ushort* __restrict__ featbf,
                 const ushort* __restrict__ Bt, const float* __restrict__ comps,
                 const float* __restrict__ bias, float* __restrict__ out) {
  __shared__ ushort aggs[kTN * kKT];
  __shared__ float  cvb[kTN][17][kNB];
  int tid  = threadIdx.x;
  int wv   = tid >> 6;
  int lane = tid & 63;
  int node0 = blockIdx.x * kTN;

  for (int q = tid; q < kTN * 17; q += 512) {
    int nl = q / 17, rl = q - nl * 17;
    float val = 0.f;
    if (rl < kNRel) {
      int idx = (node0 + nl) * kNRel + rl;
      int d = rp[idx + 1] - rp[idx];
      val = d > 0 ? 1.0f / (float)d : 0.f;
    }
#pragma unroll
    for (int b = 0; b < kNB; ++b)
      cvb[nl][rl][b] = comps[rl * kNB + b] * val;
  }
  __syncthreads();

  for (int half = 0; half < 2; ++half) {
    int nl   = (wv << 1) | half;
    int node = node0 + nl;
    int e0 = rp[node * kNRel];
    int e1 = rp[node * kNRel + kNRel];

    float4 f = *reinterpret_cast<const float4*>(feat + (size_t)node * kIN + lane * 4);
    float4 acc[kNB];
#pragma unroll
    for (int b = 0; b < kNB; ++b) {
      float cs = comps[2*kR0*kNB + b];
      acc[b].x = cs * f.x; acc[b].y = cs * f.y; acc[b].z = cs * f.z; acc[b].w = cs * f.w;
    }
    const float4* cvr = reinterpret_cast<const float4*>(&cvb[nl][0][0]);
    const int pad = (16 << 16);
    int cc[4];
#pragma unroll
    for (int j = 0; j < 4; ++j) {
      int ee = e0 + j;
      int v  = col[ee < kMsgs ? ee : kMsgs - 1];
      cc[j] = ee < e1 ? v : pad;
    }
    for (int e = e0; e < e1; e += 4) {
      uint2 g[4];
#pragma unroll
      for (int j = 0; j < 4; ++j) {
        int sn = cc[j] & 0xFFFF;
        g[j] = *reinterpret_cast<const uint2*>(featbf + (size_t)sn * kIN + lane * 4);
      }
      int rr[4];
#pragma unroll
      for (int j = 0; j < 4; ++j) rr[j] = cc[j] >> 16;
#pragma unroll
      for (int j = 0; j < 4; ++j) {
        int ee = e + 4 + j;
        int v  = col[ee < kMsgs ? ee : kMsgs - 1];
        cc[j] = ee < e1 ? v : pad;
      }
#pragma unroll
      for (int j = 0; j < 4; ++j) {
        float4 c0 = cvr[rr[j] * 2];
        float4 c1 = cvr[rr[j] * 2 + 1];
        float4 gg;
        gg.x = __uint_as_float(g[j].x << 16);
        gg.y = __uint_as_float(g[j].x & 0xFFFF0000u);
        gg.z = __uint_as_float(g[j].y << 16);
        gg.w = __uint_as_float(g[j].y & 0xFFFF0000u);
        FMA4(acc[0], c0.x, gg) FMA4(acc[1], c0.y, gg)
        FMA4(acc[2], c0.z, gg) FMA4(acc[3], c0.w, gg)
        FMA4(acc[4], c1.x, gg) FMA4(acc[5], c1.y, gg)
        FMA4(acc[6], c1.z, gg) FMA4(acc[7], c1.w, gg)
      }
    }
    int xr = (nl & 7) << 4;
#pragma unroll
    for (int b = 0; b < kNB; ++b) {
      ushort4 p;
      p.x = f2bf(acc[b].x); p.y = f2bf(acc[b].y);
      p.z = f2bf(acc[b].z); p.w = f2bf(acc[b].w);
      int byteoff = nl * 4096 + ((b * 512 + lane * 8) ^ xr);
      *reinterpret_cast<ushort4*>(reinterpret_cast<char*>(aggs) + byteoff) = p;
    }
  }
  __syncthreads();

  {
    int n  = lane & 15;
    int g4 = lane >> 4;
    const char* abase = reinterpret_cast<const char*>(aggs) + n * 4096;
    int axor = (n & 7) << 4;
#pragma unroll
    for (int t = 0; t < 2; ++t) {
      int ntile = wv + t * 8;
      float bi = bias[ntile * 16 + n];
      const char* btrow = reinterpret_cast<const char*>(Bt)
                          + (size_t)(ntile * 16 + n) * 4096;
      int bxor = (n & 7) << 4;
      f32x4 acc = {0.f, 0.f, 0.f, 0.f};
#pragma unroll 4
      for (int ks = 0; ks < kKT / 32; ++ks) {
        int kb = ks * 64 + g4 * 16;
        bf16x8 af = *reinterpret_cast<const bf16x8*>(abase + (kb ^ axor));
        bf16x8 bf = *reinterpret_cast<const bf16x8*>(btrow + (kb ^ bxor));
        acc = __builtin_amdgcn_mfma_f32_16x16x32_bf16(af, bf, acc, 0, 0, 0);
      }
#pragma unroll
      for (int j = 0; j < 4; ++j) {
        int row = g4 * 4 + j;
        out[(size_t)(node0 + row) * kOUT + ntile * 16 + n] = acc[j] + bi;
      }
    }
  }
}

// ---------------- launch ----------------

extern "C" void kernel_launch(void* const* d_in, const int* in_sizes, int n_in,
                              void* d_out, int out_size, void* d_ws, size_t ws_size,
                              hipStream_t stream) {
  const int*   triples = (const int*)  d_in[0];
  const float* feat    = (const float*)d_in[1];
  const float* bases   = (const float*)d_in[2];
  const float* comps   = (const float*)d_in[3];
  const float* bias    = (const float*)d_in[4];
  float* out = (float*)d_out;

  size_t featbf_b = (size_t)kN * kIN * 2;        // 15,360,000
  size_t bt_b     = (size_t)kOUT * kKT * 2;      // 1,048,576
  size_t aggb_b   = (size_t)kMPad * kKT * 2;     // 122,945,536
  size_t csr_b    = (size_t)(kRows + kRows + 1 + kMsgs + kNScanBlk) * 4;
  bool bigws = ws_size >= featbf_b + bt_b + aggb_b + csr_b + 1024;

  char* p = (char*)d_ws;
  ushort* featbf = (ushort*)p;            p += featbf_b;
  ushort* Bt     = (ushort*)p;            p += bt_b;
  ushort* aggb   = nullptr;
  if (bigws) { aggb = (ushort*)p;         p += aggb_b; }
  int* deg    = (int*)p;
  int* rp     = deg + kRows;
  int* col    = rp + kRows + 1;
  int* blksum = col + kMsgs;

  hipMemsetAsync(deg, 0, kRows * sizeof(int), stream);
  k_prep  <<<(kN * kIN / 4 + 255) / 256, 256, 0, stream>>>(feat, featbf, triples, deg);
  k_bt    <<<kKT / 16,            256, 0, stream>>>(bases, Bt);
  k_scan1 <<<kNScanBlk,           256, 0, stream>>>(deg, rp, blksum);
  k_scan2 <<<1,                   512, 0, stream>>>(blksum);
  k_scan3 <<<(kRows + 256) / 256, 256, 0, stream>>>(rp, blksum);
  k_scatter<<<(kMsgs + 255) / 256, 256, 0, stream>>>(triples, rp, deg, col);

  if (bigws) {
    k_agg1<<<kN / 4,  256, 0, stream>>>(rp, col, featbf, comps, aggb);
    k_gemm<<<kMB,     512, 0, stream>>>(aggb, Bt, bias, out);
  } else {
    k_out_fused<<<kN / kTN, 512, 0, stream>>>(rp, col, feat, featbf, Bt,
                                              comps, bias, out);
  }
}